// Round 2
// baseline (2098.229 us; speedup 1.0000x reference)
//
#include <hip/hip_runtime.h>
#include <hip/hip_bf16.h>

#define NN 8192
#define CC 384
#define KD 512
#define HWP 1024

static constexpr float T_OVER_N = 10.0f / 8192.0f;

__device__ __forceinline__ float bf2f(unsigned short u) {
    union { unsigned int i; float f; } x;
    x.i = ((unsigned int)u) << 16;
    return x.f;
}
__device__ __forceinline__ unsigned short f2bf(float f) {
    __hip_bfloat16 h = __float2bfloat16(f);
    unsigned short u;
    __builtin_memcpy(&u, &h, sizeof(u));
    return u;
}

// ---------------- row-normalize FF -> FFn ----------------
__global__ __launch_bounds__(128) void k_normalize(const float* __restrict__ FF,
                                                   float* __restrict__ FFn) {
    int row = blockIdx.x;
    int tid = threadIdx.x;
    const float* src = FF + (size_t)row * CC;
    float v0 = src[tid], v1 = src[tid + 128], v2 = src[tid + 256];
    float s = v0 * v0 + v1 * v1 + v2 * v2;
    #pragma unroll
    for (int off = 32; off > 0; off >>= 1) s += __shfl_down(s, off, 64);
    __shared__ float ls[2];
    if ((tid & 63) == 0) ls[tid >> 6] = s;
    __syncthreads();
    float inv = 1.0f / sqrtf(ls[0] + ls[1]);
    float* dst = FFn + (size_t)row * CC;
    dst[tid] = v0 * inv;
    dst[tid + 128] = v1 * inv;
    dst[tid + 256] = v2 * inv;
}

// ---------------- per-row kNN selection (two variants) ----------------
__global__ __launch_bounds__(256) void k_knn(const float* __restrict__ im,
                                             unsigned char* __restrict__ res20,
                                             unsigned char* __restrict__ res10) {
    const int p = blockIdx.x;   // pixel row 0..1023
    const int b = blockIdx.y;   // image 0..7
    const int v = blockIdx.z;   // variant 0:(k=20,dw=2.0) 1:(k=10,dw=0.1)
    const float dw = v ? 0.1f : 2.0f;
    const int kneigh = v ? 10 : 20;
    __shared__ float d2[HWP];
    __shared__ unsigned char sel[HWP];
    __shared__ float bval[256];
    __shared__ int bidx[256];
    const float* im0 = im + (size_t)b * 3 * HWP;
    const float scale = dw * (1.0f / 31.0f);
    float rf0 = (im0[p] + 1.f) * 0.5f;
    float rf1 = (im0[HWP + p] + 1.f) * 0.5f;
    float rf2 = (im0[2 * HWP + p] + 1.f) * 0.5f;
    float rx = (float)(p & 31) * scale;
    float ry = (float)(p >> 5) * scale;
    for (int q = threadIdx.x; q < HWP; q += 256) {
        float f0 = (im0[q] + 1.f) * 0.5f - rf0;
        float f1 = (im0[HWP + q] + 1.f) * 0.5f - rf1;
        float f2 = (im0[2 * HWP + q] + 1.f) * 0.5f - rf2;
        float fx = (float)(q & 31) * scale - rx;
        float fy = (float)(q >> 5) * scale - ry;
        float d = f0 * f0 + f1 * f1 + f2 * f2 + fx * fx + fy * fy;
        d2[q] = (q == p) ? 3.4e38f : d;
        sel[q] = 0;
    }
    __syncthreads();
    for (int it = 0; it < kneigh; ++it) {
        float best = 3.5e38f;
        int bi = 1 << 30;
        for (int q = threadIdx.x; q < HWP; q += 256) {
            float dv = d2[q];
            if (dv < best) { best = dv; bi = q; }   // strict < keeps lowest idx on tie
        }
        bval[threadIdx.x] = best;
        bidx[threadIdx.x] = bi;
        __syncthreads();
        for (int s = 128; s > 0; s >>= 1) {
            if (threadIdx.x < s) {
                float ov = bval[threadIdx.x + s];
                int oi = bidx[threadIdx.x + s];
                float mv = bval[threadIdx.x];
                int mi = bidx[threadIdx.x];
                if (ov < mv || (ov == mv && oi < mi)) {
                    bval[threadIdx.x] = ov;
                    bidx[threadIdx.x] = oi;
                }
            }
            __syncthreads();
        }
        if (threadIdx.x == 0) {
            int w = bidx[0];
            sel[w] = 1;
            d2[w] = 3.4e38f;
        }
        __syncthreads();
    }
    unsigned char* dst = (v ? res10 : res20) + ((size_t)(b * HWP + p)) * HWP;
    int q4 = threadIdx.x * 4;
    uchar4 u;
    u.x = sel[q4]; u.y = sel[q4 + 1]; u.z = sel[q4 + 2]; u.w = sel[q4 + 3];
    *(uchar4*)(dst + q4) = u;
}

// ---------------- A = relu(offdiag(FFn FFn^T)) + 0.1*blockdiag(kNN); rowsum ----------------
__global__ __launch_bounds__(256) void k_gram(const float* __restrict__ FFn,
                                              const unsigned char* __restrict__ res20,
                                              const unsigned char* __restrict__ res10,
                                              unsigned short* __restrict__ A,
                                              float* __restrict__ rowsum) {
    __shared__ float At[32][68];
    __shared__ float Bt[32][68];
    __shared__ float rsum[64][16];
    const int tj = blockIdx.x, ti = blockIdx.y;
    const int tid = threadIdx.x;
    const int tx = tid & 15, ty = tid >> 4;
    const int row0 = ti * 64, col0 = tj * 64;
    float acc[4][4] = {};
    for (int k0 = 0; k0 < CC; k0 += 32) {
        #pragma unroll
        for (int l0 = 0; l0 < 2; ++l0) {
            int l = tid + l0 * 256;
            int r = l >> 3, c4 = (l & 7) * 4;
            float4 va = *(const float4*)(FFn + (size_t)(row0 + r) * CC + k0 + c4);
            At[c4 + 0][r] = va.x; At[c4 + 1][r] = va.y; At[c4 + 2][r] = va.z; At[c4 + 3][r] = va.w;
            float4 vb = *(const float4*)(FFn + (size_t)(col0 + r) * CC + k0 + c4);
            Bt[c4 + 0][r] = vb.x; Bt[c4 + 1][r] = vb.y; Bt[c4 + 2][r] = vb.z; Bt[c4 + 3][r] = vb.w;
        }
        __syncthreads();
        #pragma unroll
        for (int kk = 0; kk < 32; ++kk) {
            float4 a = *(const float4*)&At[kk][ty * 4];
            float4 bq = *(const float4*)&Bt[kk][tx * 4];
            float av[4] = {a.x, a.y, a.z, a.w};
            float bv[4] = {bq.x, bq.y, bq.z, bq.w};
            #pragma unroll
            for (int r = 0; r < 4; ++r)
                #pragma unroll
                for (int c = 0; c < 4; ++c)
                    acc[r][c] += av[r] * bv[c];
        }
        __syncthreads();
    }
    const bool diagBlk = (row0 >> 10) == (col0 >> 10);
    const int bimg = row0 >> 10;
    float rp[4];
    #pragma unroll
    for (int r = 0; r < 4; ++r) {
        int gi = row0 + ty * 4 + r;
        float rs = 0.f;
        #pragma unroll
        for (int c = 0; c < 4; ++c) {
            int gj = col0 + tx * 4 + c;
            float vv = acc[r][c];
            vv = (gi == gj) ? 0.f : fmaxf(vv, 0.f);
            if (diagBlk) {
                int li = gi & 1023, lj = gj & 1023;
                size_t base = ((size_t)bimg) << 20;
                unsigned char m = (unsigned char)(
                    (res20[base + (size_t)li * HWP + lj] & res20[base + (size_t)lj * HWP + li]) |
                    (res10[base + (size_t)li * HWP + lj] & res10[base + (size_t)lj * HWP + li]));
                vv += 0.1f * (float)m;
            }
            A[(size_t)gi * NN + gj] = f2bf(vv);
            rs += vv;
        }
        rp[r] = rs;
    }
    #pragma unroll
    for (int r = 0; r < 4; ++r) rsum[ty * 4 + r][tx] = rp[r];
    __syncthreads();
    if (tid < 64) {
        float s = 0.f;
        #pragma unroll
        for (int t = 0; t < 16; ++t) s += rsum[tid][t];
        atomicAdd(&rowsum[row0 + tid], s);
    }
}

// ---------------- D = rsqrt(rowsum/(N-1)) ----------------
__global__ __launch_bounds__(256) void k_d(const float* __restrict__ rowsum,
                                           float* __restrict__ Dv) {
    int i = blockIdx.x * 256 + threadIdx.x;
    Dv[i] = 1.0f / sqrtf(rowsum[i] * (1.0f / 8191.0f));
}

// ---------------- Y = diag(D) A diag(D) Psi_s ----------------
__global__ __launch_bounds__(256) void k_y(const unsigned short* __restrict__ A,
                                           const float* __restrict__ Psi,
                                           const float* __restrict__ Dv,
                                           float* __restrict__ Y) {
    __shared__ float At[32][68];
    __shared__ float Bt[32][68];
    const int kt = blockIdx.x, it = blockIdx.y;
    const int tid = threadIdx.x, tx = tid & 15, ty = tid >> 4;
    const int row0 = it * 64, k0 = kt * 64;
    float acc[4][4] = {};
    for (int j0 = 0; j0 < NN; j0 += 32) {
        {
            int r = tid >> 2, sg = (tid & 3) * 8;
            uint4 u = *(const uint4*)(A + (size_t)(row0 + r) * NN + j0 + sg);
            At[sg + 0][r] = bf2f((unsigned short)(u.x & 0xffff));
            At[sg + 1][r] = bf2f((unsigned short)(u.x >> 16));
            At[sg + 2][r] = bf2f((unsigned short)(u.y & 0xffff));
            At[sg + 3][r] = bf2f((unsigned short)(u.y >> 16));
            At[sg + 4][r] = bf2f((unsigned short)(u.z & 0xffff));
            At[sg + 5][r] = bf2f((unsigned short)(u.z >> 16));
            At[sg + 6][r] = bf2f((unsigned short)(u.w & 0xffff));
            At[sg + 7][r] = bf2f((unsigned short)(u.w >> 16));
        }
        #pragma unroll
        for (int l0 = 0; l0 < 2; ++l0) {
            int l = tid + l0 * 256;
            int j = l >> 4, c4 = (l & 15) * 4;
            float sc = Dv[j0 + j] * T_OVER_N;
            float4 v = *(const float4*)(Psi + (size_t)(j0 + j) * KD + k0 + c4);
            Bt[j][c4 + 0] = v.x * sc; Bt[j][c4 + 1] = v.y * sc;
            Bt[j][c4 + 2] = v.z * sc; Bt[j][c4 + 3] = v.w * sc;
        }
        __syncthreads();
        #pragma unroll
        for (int kk = 0; kk < 32; ++kk) {
            float4 a = *(const float4*)&At[kk][ty * 4];
            float4 bq = *(const float4*)&Bt[kk][tx * 4];
            float av[4] = {a.x, a.y, a.z, a.w};
            float bv[4] = {bq.x, bq.y, bq.z, bq.w};
            #pragma unroll
            for (int r = 0; r < 4; ++r)
                #pragma unroll
                for (int c = 0; c < 4; ++c)
                    acc[r][c] += av[r] * bv[c];
        }
        __syncthreads();
    }
    #pragma unroll
    for (int r = 0; r < 4; ++r) {
        int gi = row0 + ty * 4 + r;
        float di = Dv[gi];
        float4 o;
        o.x = di * acc[r][0]; o.y = di * acc[r][1];
        o.z = di * acc[r][2]; o.w = di * acc[r][3];
        *(float4*)(Y + (size_t)gi * KD + k0 + tx * 4) = o;
    }
}

// ---------------- R = Psi_s^T Y, reduced to trace & triu-square-sum ----------------
__global__ __launch_bounds__(256) void k_r(const float* __restrict__ Psi,
                                           const float* __restrict__ Y,
                                           float* __restrict__ acc2) {
    const int t2 = blockIdx.x, t1 = blockIdx.y;
    if (t1 > t2) return;
    __shared__ float Pt[32][68];
    __shared__ float Yt[32][68];
    __shared__ float red[256];
    const int tid = threadIdx.x, tx = tid & 15, ty = tid >> 4;
    const int c1 = t1 * 64, c2 = t2 * 64;
    float acc[4][4] = {};
    for (int i0 = 0; i0 < NN; i0 += 32) {
        #pragma unroll
        for (int l0 = 0; l0 < 2; ++l0) {
            int l = tid + l0 * 256;
            int i = l >> 4, c4 = (l & 15) * 4;
            float4 pv = *(const float4*)(Psi + (size_t)(i0 + i) * KD + c1 + c4);
            Pt[i][c4 + 0] = pv.x * T_OVER_N; Pt[i][c4 + 1] = pv.y * T_OVER_N;
            Pt[i][c4 + 2] = pv.z * T_OVER_N; Pt[i][c4 + 3] = pv.w * T_OVER_N;
            float4 yv = *(const float4*)(Y + (size_t)(i0 + i) * KD + c2 + c4);
            Yt[i][c4 + 0] = yv.x; Yt[i][c4 + 1] = yv.y;
            Yt[i][c4 + 2] = yv.z; Yt[i][c4 + 3] = yv.w;
        }
        __syncthreads();
        #pragma unroll
        for (int kk = 0; kk < 32; ++kk) {
            float4 a = *(const float4*)&Pt[kk][ty * 4];
            float4 bq = *(const float4*)&Yt[kk][tx * 4];
            float av[4] = {a.x, a.y, a.z, a.w};
            float bv[4] = {bq.x, bq.y, bq.z, bq.w};
            #pragma unroll
            for (int r = 0; r < 4; ++r)
                #pragma unroll
                for (int c = 0; c < 4; ++c)
                    acc[r][c] += av[r] * bv[c];
        }
        __syncthreads();
    }
    float tr = 0.f, rg = 0.f;
    #pragma unroll
    for (int r = 0; r < 4; ++r) {
        int gk1 = c1 + ty * 4 + r;
        #pragma unroll
        for (int c = 0; c < 4; ++c) {
            int gk2 = c2 + tx * 4 + c;
            float vv = acc[r][c];
            if (gk1 == gk2) tr += vv;
            else if (gk1 < gk2) rg += vv * vv;
        }
    }
    red[tid] = tr; __syncthreads();
    for (int s = 128; s > 0; s >>= 1) { if (tid < s) red[tid] += red[tid + s]; __syncthreads(); }
    if (tid == 0) atomicAdd(&acc2[0], red[0]);
    __syncthreads();
    red[tid] = rg; __syncthreads();
    for (int s = 128; s > 0; s >>= 1) { if (tid < s) red[tid] += red[tid + s]; __syncthreads(); }
    if (tid == 0) atomicAdd(&acc2[1], red[0]);
}

// ---------------- finalize (d_out is float32: reference returns float32 stack) ----------------
__global__ void k_fin(const float* __restrict__ acc2, float* __restrict__ out) {
    out[0] = -acc2[0];
    out[1] = 0.05f * acc2[1];
}

extern "C" void kernel_launch(void* const* d_in, const int* in_sizes, int n_in,
                              void* d_out, int out_size, void* d_ws, size_t ws_size,
                              hipStream_t stream) {
    const float* FF  = (const float*)d_in[0];
    const float* Psi = (const float*)d_in[1];
    const float* im  = (const float*)d_in[2];
    float* out = (float*)d_out;
    char* ws = (char*)d_ws;
    size_t off = 0;
    auto alloc = [&](size_t bytes) {
        size_t o = off;
        off += (bytes + 255) & ~(size_t)255;
        return o;
    };
    float* FFn            = (float*)(ws + alloc((size_t)NN * CC * 4));
    unsigned char* res20  = (unsigned char*)(ws + alloc((size_t)8 * HWP * HWP));
    unsigned char* res10  = (unsigned char*)(ws + alloc((size_t)8 * HWP * HWP));
    float* rowsum         = (float*)(ws + alloc((size_t)NN * 4));
    float* Dv             = (float*)(ws + alloc((size_t)NN * 4));
    float* Y              = (float*)(ws + alloc((size_t)NN * KD * 4));
    float* acc2           = (float*)(ws + alloc(256));
    unsigned short* A     = (unsigned short*)(ws + alloc((size_t)NN * NN * 2));

    hipMemsetAsync(rowsum, 0, (size_t)NN * 4, stream);
    hipMemsetAsync(acc2, 0, 8, stream);

    k_normalize<<<NN, 128, 0, stream>>>(FF, FFn);
    k_knn<<<dim3(HWP, 8, 2), 256, 0, stream>>>(im, res20, res10);
    k_gram<<<dim3(128, 128), 256, 0, stream>>>(FFn, res20, res10, A, rowsum);
    k_d<<<NN / 256, 256, 0, stream>>>(rowsum, Dv);
    k_y<<<dim3(8, 128), 256, 0, stream>>>(A, Psi, Dv, Y);
    k_r<<<dim3(8, 8), 256, 0, stream>>>(Psi, Y, acc2);
    k_fin<<<1, 1, 0, stream>>>(acc2, out);
}

// Round 3
// 531.400 us; speedup vs baseline: 3.9485x; 3.9485x over previous
//
#include <hip/hip_runtime.h>
#include <hip/hip_bf16.h>

#define NN 8192
#define CC 384
#define KD 512
#define HWP 1024

typedef __attribute__((ext_vector_type(8))) short bf16x8;
typedef __attribute__((ext_vector_type(4))) float f32x4;

static constexpr float T_OVER_N = 10.0f / 8192.0f;

__device__ __forceinline__ float bf2f(unsigned short u) {
    union { unsigned int i; float f; } x;
    x.i = ((unsigned int)u) << 16;
    return x.f;
}
__device__ __forceinline__ unsigned short f2bf(float f) {
    __hip_bfloat16 h = __float2bfloat16(f);
    unsigned short u;
    __builtin_memcpy(&u, &h, sizeof(u));
    return u;
}

// ---------- 128x64 bf16 tile staging via global_load_lds (16B), source-side XOR swizzle ----------
// LDS layout: row r (128B) holds its 8 16B-chunks permuted by c_stored = c_logical ^ (r&7).
// global_load_lds writes linearly (wave base + lane*16), so the swizzle is applied to the
// per-lane GLOBAL source address (rule #21: inverse-swz source + swz read).
__device__ __forceinline__ void stage_tile(const unsigned short* __restrict__ src, long ld,
                                           int k0, unsigned short* lds) {
    const int t = threadIdx.x;  // blockDim == 256
    #pragma unroll
    for (int i = 0; i < 4; ++i) {
        int slot = i * 256 + t;          // 16B slot 0..1023 (8 per row)
        int row = slot >> 3;
        int cl = (slot & 7) ^ (row & 7); // logical chunk for this stored slot
        const unsigned short* g = src + (long)row * ld + k0 + cl * 8;
        __builtin_amdgcn_global_load_lds((const __attribute__((address_space(1))) void*)g,
                                         (__attribute__((address_space(3))) void*)(lds + (size_t)slot * 8),
                                         16, 0, 0);
    }
}

// swizzled fragment read: row r (0..127), chunk (0..7) -> 8 bf16
__device__ __forceinline__ bf16x8 read_frag(const unsigned short* lds, int r, int chunk) {
    int byte = (r << 7) + (((chunk ^ r) & 7) << 4) + ((chunk & ~7) << 4);
    return *(const bf16x8*)((const char*)lds + byte);
}

// one BK=64 step: 32 ds_read_b128 + 32 MFMA per wave (16 frags x 2 k-slots)
__device__ __forceinline__ void gemm_step(const unsigned short* As, const unsigned short* Bs,
                                          int arl, int brl, int lhi, f32x4 (&acc)[4][4]) {
    #pragma unroll
    for (int ks = 0; ks < 2; ++ks) {
        bf16x8 a[4], b[4];
        #pragma unroll
        for (int m = 0; m < 4; ++m) a[m] = read_frag(As, arl + m * 16, ks * 4 + lhi);
        #pragma unroll
        for (int n = 0; n < 4; ++n) b[n] = read_frag(Bs, brl + n * 16, ks * 4 + lhi);
        #pragma unroll
        for (int m = 0; m < 4; ++m)
            #pragma unroll
            for (int n = 0; n < 4; ++n)
                acc[m][n] = __builtin_amdgcn_mfma_f32_16x16x32_bf16(a[m], b[n], acc[m][n], 0, 0, 0);
    }
}

// ---------------- row-normalize FF -> bf16 FFnb ----------------
__global__ __launch_bounds__(128) void k_normalize(const float* __restrict__ FF,
                                                   unsigned short* __restrict__ FFnb) {
    int row = blockIdx.x;
    int tid = threadIdx.x;
    const float* src = FF + (size_t)row * CC;
    float v0 = src[tid], v1 = src[tid + 128], v2 = src[tid + 256];
    float s = v0 * v0 + v1 * v1 + v2 * v2;
    #pragma unroll
    for (int off = 32; off > 0; off >>= 1) s += __shfl_down(s, off, 64);
    __shared__ float ls[2];
    if ((tid & 63) == 0) ls[tid >> 6] = s;
    __syncthreads();
    float inv = 1.0f / sqrtf(ls[0] + ls[1]);
    unsigned short* dst = FFnb + (size_t)row * CC;
    dst[tid] = f2bf(v0 * inv);
    dst[tid + 128] = f2bf(v1 * inv);
    dst[tid + 256] = f2bf(v2 * inv);
}

// ---------------- per-row kNN selection (two variants) ----------------
__global__ __launch_bounds__(256) void k_knn(const float* __restrict__ im,
                                             unsigned char* __restrict__ res20,
                                             unsigned char* __restrict__ res10) {
    const int p = blockIdx.x;
    const int b = blockIdx.y;
    const int v = blockIdx.z;
    const float dw = v ? 0.1f : 2.0f;
    const int kneigh = v ? 10 : 20;
    __shared__ float d2[HWP];
    __shared__ unsigned char sel[HWP];
    __shared__ float bval[256];
    __shared__ int bidx[256];
    const float* im0 = im + (size_t)b * 3 * HWP;
    const float scale = dw * (1.0f / 31.0f);
    float rf0 = (im0[p] + 1.f) * 0.5f;
    float rf1 = (im0[HWP + p] + 1.f) * 0.5f;
    float rf2 = (im0[2 * HWP + p] + 1.f) * 0.5f;
    float rx = (float)(p & 31) * scale;
    float ry = (float)(p >> 5) * scale;
    for (int q = threadIdx.x; q < HWP; q += 256) {
        float f0 = (im0[q] + 1.f) * 0.5f - rf0;
        float f1 = (im0[HWP + q] + 1.f) * 0.5f - rf1;
        float f2 = (im0[2 * HWP + q] + 1.f) * 0.5f - rf2;
        float fx = (float)(q & 31) * scale - rx;
        float fy = (float)(q >> 5) * scale - ry;
        float d = f0 * f0 + f1 * f1 + f2 * f2 + fx * fx + fy * fy;
        d2[q] = (q == p) ? 3.4e38f : d;
        sel[q] = 0;
    }
    __syncthreads();
    for (int it = 0; it < kneigh; ++it) {
        float best = 3.5e38f;
        int bi = 1 << 30;
        for (int q = threadIdx.x; q < HWP; q += 256) {
            float dv = d2[q];
            if (dv < best) { best = dv; bi = q; }
        }
        bval[threadIdx.x] = best;
        bidx[threadIdx.x] = bi;
        __syncthreads();
        for (int s = 128; s > 0; s >>= 1) {
            if (threadIdx.x < s) {
                float ov = bval[threadIdx.x + s];
                int oi = bidx[threadIdx.x + s];
                float mv = bval[threadIdx.x];
                int mi = bidx[threadIdx.x];
                if (ov < mv || (ov == mv && oi < mi)) {
                    bval[threadIdx.x] = ov;
                    bidx[threadIdx.x] = oi;
                }
            }
            __syncthreads();
        }
        if (threadIdx.x == 0) {
            int w = bidx[0];
            sel[w] = 1;
            d2[w] = 3.4e38f;
        }
        __syncthreads();
    }
    unsigned char* dst = (v ? res10 : res20) + ((size_t)(b * HWP + p)) * HWP;
    int q4 = threadIdx.x * 4;
    uchar4 u;
    u.x = sel[q4]; u.y = sel[q4 + 1]; u.z = sel[q4 + 2]; u.w = sel[q4 + 3];
    *(uchar4*)(dst + q4) = u;
}

// ---------------- A = relu(offdiag(FFn FFn^T)) + 0.1*blockdiag(kNN)  [MFMA 128x128 tile] ----------------
__global__ __launch_bounds__(256, 2) void k_gram(const unsigned short* __restrict__ FFnb,
                                                 const unsigned char* __restrict__ res20,
                                                 const unsigned char* __restrict__ res10,
                                                 unsigned short* __restrict__ A) {
    __shared__ __align__(16) unsigned short As[128 * 64];
    __shared__ __align__(16) unsigned short Bs[128 * 64];
    int fid = blockIdx.y * gridDim.x + blockIdx.x;
    int s = (fid & 7) * 512 + (fid >> 3);          // XCD swizzle, 4096 % 8 == 0
    const int ti = s >> 6, tj = s & 63;
    const int row0 = ti * 128, col0 = tj * 128;
    const int tid = threadIdx.x, l = tid & 63, wid = tid >> 6;
    const int wr = (wid >> 1) * 64, wc = (wid & 1) * 64;
    const int arl = wr + (l & 15), brl = wc + (l & 15), lhi = l >> 4;
    f32x4 z = {0.f, 0.f, 0.f, 0.f};
    f32x4 acc[4][4];
    #pragma unroll
    for (int m = 0; m < 4; ++m)
        #pragma unroll
        for (int n = 0; n < 4; ++n) acc[m][n] = z;

    for (int k0 = 0; k0 < CC; k0 += 64) {
        stage_tile(FFnb + (long)row0 * CC, CC, k0, As);
        stage_tile(FFnb + (long)col0 * CC, CC, k0, Bs);
        __syncthreads();
        gemm_step(As, Bs, arl, brl, lhi, acc);
        __syncthreads();
    }
    const bool diagBlk = (row0 >> 10) == (col0 >> 10);
    const long mbase = ((long)(row0 >> 10)) << 20;
    #pragma unroll
    for (int m = 0; m < 4; ++m) {
        #pragma unroll
        for (int n = 0; n < 4; ++n) {
            #pragma unroll
            for (int r = 0; r < 4; ++r) {
                int gi = row0 + wr + m * 16 + lhi * 4 + r;
                int gj = col0 + wc + n * 16 + (l & 15);
                float vv = acc[m][n][r];
                vv = (gi == gj) ? 0.f : fmaxf(vv, 0.f);
                if (diagBlk) {
                    int li = gi & 1023, lj = gj & 1023;
                    unsigned char mm = (unsigned char)(
                        (res20[mbase + (long)li * HWP + lj] & res20[mbase + (long)lj * HWP + li]) |
                        (res10[mbase + (long)li * HWP + lj] & res10[mbase + (long)lj * HWP + li]));
                    vv += 0.1f * (float)mm;
                }
                A[(long)gi * NN + gj] = f2bf(vv);
            }
        }
    }
}

// ---------------- rowsum of bf16 A ----------------
__global__ __launch_bounds__(256) void k_rowsum(const unsigned short* __restrict__ A,
                                                float* __restrict__ rowsum) {
    const int row = blockIdx.x;
    const unsigned short* src = A + (long)row * NN;
    const int tid = threadIdx.x;
    float s = 0.f;
    #pragma unroll
    for (int i = 0; i < 4; ++i) {
        bf16x8 v = *(const bf16x8*)(src + (size_t)(i * 256 + tid) * 8);
        #pragma unroll
        for (int e = 0; e < 8; ++e) s += bf2f((unsigned short)v[e]);
    }
    #pragma unroll
    for (int off = 32; off > 0; off >>= 1) s += __shfl_down(s, off, 64);
    __shared__ float ls[4];
    if ((tid & 63) == 0) ls[tid >> 6] = s;
    __syncthreads();
    if (tid == 0) rowsum[row] = ls[0] + ls[1] + ls[2] + ls[3];
}

// ---------------- D = rsqrt(rowsum/(N-1)) ----------------
__global__ __launch_bounds__(256) void k_d(const float* __restrict__ rowsum,
                                           float* __restrict__ Dv) {
    int i = blockIdx.x * 256 + threadIdx.x;
    Dv[i] = 1.0f / sqrtf(rowsum[i] * (1.0f / 8191.0f));
}

// ---------------- Psi transposes: PaT = (T/N)*Psi^T, PsT = (T/N)*diag-scaled Psi^T (bf16) ----------------
__global__ __launch_bounds__(256) void k_psiT(const float* __restrict__ Psi,
                                              const float* __restrict__ Dv,
                                              unsigned short* __restrict__ PaT,
                                              unsigned short* __restrict__ PsT) {
    const int n = blockIdx.x;  // 0..511
    for (int j = threadIdx.x; j < NN; j += 256) {
        float p = Psi[(long)j * KD + n] * T_OVER_N;
        PaT[(long)n * NN + j] = f2bf(p);
        PsT[(long)n * NN + j] = f2bf(p * Dv[j]);
    }
}

// ---------------- YT[n][i] = Dv[i] * sum_j PsT[n][j] * A[i][j]   (A symmetric) ----------------
__global__ __launch_bounds__(256, 2) void k_yt(const unsigned short* __restrict__ PsT,
                                               const unsigned short* __restrict__ A,
                                               const float* __restrict__ Dv,
                                               unsigned short* __restrict__ YT) {
    __shared__ __align__(16) unsigned short As[128 * 64];
    __shared__ __align__(16) unsigned short Bs[128 * 64];
    int s = (blockIdx.x & 7) * 32 + (blockIdx.x >> 3);   // XCD swizzle, 256 % 8 == 0
    const int nt = s >> 6, it = s & 63;
    const int row0 = nt * 128, col0 = it * 128;
    const int tid = threadIdx.x, l = tid & 63, wid = tid >> 6;
    const int wr = (wid >> 1) * 64, wc = (wid & 1) * 64;
    const int arl = wr + (l & 15), brl = wc + (l & 15), lhi = l >> 4;
    f32x4 z = {0.f, 0.f, 0.f, 0.f};
    f32x4 acc[4][4];
    #pragma unroll
    for (int m = 0; m < 4; ++m)
        #pragma unroll
        for (int n = 0; n < 4; ++n) acc[m][n] = z;

    for (int k0 = 0; k0 < NN; k0 += 64) {
        stage_tile(PsT + (long)row0 * NN, NN, k0, As);
        stage_tile(A + (long)col0 * NN, NN, k0, Bs);
        __syncthreads();
        gemm_step(As, Bs, arl, brl, lhi, acc);
        __syncthreads();
    }
    #pragma unroll
    for (int m = 0; m < 4; ++m) {
        #pragma unroll
        for (int n = 0; n < 4; ++n) {
            #pragma unroll
            for (int r = 0; r < 4; ++r) {
                int gi = row0 + wr + m * 16 + lhi * 4 + r;
                int gj = col0 + wc + n * 16 + (l & 15);
                YT[(long)gi * NN + gj] = f2bf(acc[m][n][r] * Dv[gj]);
            }
        }
    }
}

// ---------------- R += PaT-tile * YT-tile^T (K-split, atomic fp32) ----------------
__global__ __launch_bounds__(256, 2) void k_r(const unsigned short* __restrict__ PaT,
                                              const unsigned short* __restrict__ YT,
                                              float* __restrict__ R) {
    const int t2 = blockIdx.x, t1 = blockIdx.y, kz = blockIdx.z;
    if (t1 > t2) return;
    __shared__ __align__(16) unsigned short As[128 * 64];
    __shared__ __align__(16) unsigned short Bs[128 * 64];
    const int row0 = t1 * 128, col0 = t2 * 128;
    const int tid = threadIdx.x, l = tid & 63, wid = tid >> 6;
    const int wr = (wid >> 1) * 64, wc = (wid & 1) * 64;
    const int arl = wr + (l & 15), brl = wc + (l & 15), lhi = l >> 4;
    f32x4 z = {0.f, 0.f, 0.f, 0.f};
    f32x4 acc[4][4];
    #pragma unroll
    for (int m = 0; m < 4; ++m)
        #pragma unroll
        for (int n = 0; n < 4; ++n) acc[m][n] = z;

    const int kbeg = kz * 2048, kend = kbeg + 2048;
    for (int k0 = kbeg; k0 < kend; k0 += 64) {
        stage_tile(PaT + (long)row0 * NN, NN, k0, As);
        stage_tile(YT + (long)col0 * NN, NN, k0, Bs);
        __syncthreads();
        gemm_step(As, Bs, arl, brl, lhi, acc);
        __syncthreads();
    }
    #pragma unroll
    for (int m = 0; m < 4; ++m) {
        #pragma unroll
        for (int n = 0; n < 4; ++n) {
            #pragma unroll
            for (int r = 0; r < 4; ++r) {
                int gk1 = row0 + wr + m * 16 + lhi * 4 + r;
                int gk2 = col0 + wc + n * 16 + (l & 15);
                atomicAdd(&R[(long)gk1 * KD + gk2], acc[m][n][r]);
            }
        }
    }
}

// ---------------- trace & triu^2 reduction of R ----------------
__global__ __launch_bounds__(256) void k_tri(const float* __restrict__ R,
                                             float* __restrict__ acc2) {
    float tr = 0.f, rg = 0.f;
    for (int idx = blockIdx.x * 256 + threadIdx.x; idx < KD * KD; idx += 64 * 256) {
        int k1 = idx >> 9, k2 = idx & 511;
        float v = R[idx];
        if (k1 == k2) tr += v;
        else if (k1 < k2) rg += v * v;
    }
    #pragma unroll
    for (int off = 32; off > 0; off >>= 1) {
        tr += __shfl_down(tr, off, 64);
        rg += __shfl_down(rg, off, 64);
    }
    __shared__ float lt[4], lr[4];
    int tid = threadIdx.x;
    if ((tid & 63) == 0) { lt[tid >> 6] = tr; lr[tid >> 6] = rg; }
    __syncthreads();
    if (tid == 0) {
        atomicAdd(&acc2[0], lt[0] + lt[1] + lt[2] + lt[3]);
        atomicAdd(&acc2[1], lr[0] + lr[1] + lr[2] + lr[3]);
    }
}

// ---------------- finalize ----------------
__global__ void k_fin(const float* __restrict__ acc2, float* __restrict__ out) {
    out[0] = -acc2[0];
    out[1] = 0.05f * acc2[1];
}

extern "C" void kernel_launch(void* const* d_in, const int* in_sizes, int n_in,
                              void* d_out, int out_size, void* d_ws, size_t ws_size,
                              hipStream_t stream) {
    const float* FF  = (const float*)d_in[0];
    const float* Psi = (const float*)d_in[1];
    const float* im  = (const float*)d_in[2];
    float* out = (float*)d_out;
    char* ws = (char*)d_ws;
    size_t off = 0;
    auto alloc = [&](size_t bytes) {
        size_t o = off;
        off += (bytes + 255) & ~(size_t)255;
        return o;
    };
    unsigned short* FFnb  = (unsigned short*)(ws + alloc((size_t)NN * CC * 2));
    unsigned char* res20  = (unsigned char*)(ws + alloc((size_t)8 * HWP * HWP));
    unsigned char* res10  = (unsigned char*)(ws + alloc((size_t)8 * HWP * HWP));
    float* rowsum         = (float*)(ws + alloc((size_t)NN * 4));
    float* Dv             = (float*)(ws + alloc((size_t)NN * 4));
    unsigned short* PaT   = (unsigned short*)(ws + alloc((size_t)KD * NN * 2));
    unsigned short* PsT   = (unsigned short*)(ws + alloc((size_t)KD * NN * 2));
    unsigned short* YT    = (unsigned short*)(ws + alloc((size_t)KD * NN * 2));
    float* R              = (float*)(ws + alloc((size_t)KD * KD * 4));
    float* acc2           = (float*)(ws + alloc(256));
    unsigned short* A     = (unsigned short*)(ws + alloc((size_t)NN * NN * 2));

    hipMemsetAsync(R, 0, (size_t)KD * KD * 4, stream);
    hipMemsetAsync(acc2, 0, 8, stream);

    k_normalize<<<NN, 128, 0, stream>>>(FF, FFnb);
    k_knn<<<dim3(HWP, 8, 2), 256, 0, stream>>>(im, res20, res10);
    k_gram<<<dim3(64, 64), 256, 0, stream>>>(FFnb, res20, res10, A);
    k_rowsum<<<NN, 256, 0, stream>>>(A, rowsum);
    k_d<<<NN / 256, 256, 0, stream>>>(rowsum, Dv);
    k_psiT<<<KD, 256, 0, stream>>>(Psi, Dv, PaT, PsT);
    k_yt<<<256, 256, 0, stream>>>(PsT, A, Dv, YT);
    k_r<<<dim3(4, 4, 4), 256, 0, stream>>>(PaT, YT, R);
    k_tri<<<64, 256, 0, stream>>>(R, acc2);
    k_fin<<<1, 1, 0, stream>>>(acc2, out);
}

// Round 4
// 408.667 us; speedup vs baseline: 5.1343x; 1.3003x over previous
//
#include <hip/hip_runtime.h>
#include <hip/hip_bf16.h>

#define NN 8192
#define CC 384
#define KD 512
#define HWP 1024

typedef __attribute__((ext_vector_type(8))) short bf16x8;
typedef __attribute__((ext_vector_type(4))) float f32x4;

static constexpr float T_OVER_N = 10.0f / 8192.0f;

__device__ __forceinline__ float bf2f(unsigned short u) {
    union { unsigned int i; float f; } x;
    x.i = ((unsigned int)u) << 16;
    return x.f;
}
__device__ __forceinline__ unsigned short f2bf(float f) {
    __hip_bfloat16 h = __float2bfloat16(f);
    unsigned short u;
    __builtin_memcpy(&u, &h, sizeof(u));
    return u;
}

// ---------- 128x64 bf16 tile staging via global_load_lds (16B), source-side XOR swizzle ----------
__device__ __forceinline__ void stage_tile(const unsigned short* __restrict__ src, long ld,
                                           int k0, unsigned short* lds) {
    const int t = threadIdx.x;  // blockDim == 256
    #pragma unroll
    for (int i = 0; i < 4; ++i) {
        int slot = i * 256 + t;          // 16B slot 0..1023 (8 per row)
        int row = slot >> 3;
        int cl = (slot & 7) ^ (row & 7); // logical chunk for this stored slot
        const unsigned short* g = src + (long)row * ld + k0 + cl * 8;
        __builtin_amdgcn_global_load_lds((const __attribute__((address_space(1))) void*)g,
                                         (__attribute__((address_space(3))) void*)(lds + (size_t)slot * 8),
                                         16, 0, 0);
    }
}

__device__ __forceinline__ bf16x8 read_frag(const unsigned short* lds, int r, int chunk) {
    int byte = (r << 7) + (((chunk ^ r) & 7) << 4) + ((chunk & ~7) << 4);
    return *(const bf16x8*)((const char*)lds + byte);
}

__device__ __forceinline__ void gemm_step(const unsigned short* As, const unsigned short* Bs,
                                          int arl, int brl, int lhi, f32x4 (&acc)[4][4]) {
    #pragma unroll
    for (int ks = 0; ks < 2; ++ks) {
        bf16x8 a[4], b[4];
        #pragma unroll
        for (int m = 0; m < 4; ++m) a[m] = read_frag(As, arl + m * 16, ks * 4 + lhi);
        #pragma unroll
        for (int n = 0; n < 4; ++n) b[n] = read_frag(Bs, brl + n * 16, ks * 4 + lhi);
        #pragma unroll
        for (int m = 0; m < 4; ++m)
            #pragma unroll
            for (int n = 0; n < 4; ++n)
                acc[m][n] = __builtin_amdgcn_mfma_f32_16x16x32_bf16(a[m], b[n], acc[m][n], 0, 0, 0);
    }
}

// ---------------- row-normalize FF -> bf16 FFnb ----------------
__global__ __launch_bounds__(128) void k_normalize(const float* __restrict__ FF,
                                                   unsigned short* __restrict__ FFnb) {
    int row = blockIdx.x;
    int tid = threadIdx.x;
    const float* src = FF + (size_t)row * CC;
    float v0 = src[tid], v1 = src[tid + 128], v2 = src[tid + 256];
    float s = v0 * v0 + v1 * v1 + v2 * v2;
    #pragma unroll
    for (int off = 32; off > 0; off >>= 1) s += __shfl_down(s, off, 64);
    __shared__ float ls[2];
    if ((tid & 63) == 0) ls[tid >> 6] = s;
    __syncthreads();
    float inv = 1.0f / sqrtf(ls[0] + ls[1]);
    unsigned short* dst = FFnb + (size_t)row * CC;
    dst[tid] = f2bf(v0 * inv);
    dst[tid + 128] = f2bf(v1 * inv);
    dst[tid + 256] = f2bf(v2 * inv);
}

// ---------------- kNN: one wave per (pixel-row, image, variant) task ----------------
// Register-resident distances; selection via u64 (dist_bits<<10 | q) min-reduce:
// positive-f32 bit order == value order; embedded q gives exact lowest-index tie-break.
__global__ __launch_bounds__(256) void k_knn(const float* __restrict__ im,
                                             unsigned char* __restrict__ res20,
                                             unsigned char* __restrict__ res10) {
    const int lane = threadIdx.x & 63;
    const int id = blockIdx.x * 4 + (threadIdx.x >> 6);   // 0..16383
    const int v = id & 1;
    const int rest = id >> 1;
    const int p = rest & 1023;
    const int b = rest >> 10;
    const float dw = v ? 0.1f : 2.0f;
    const int kneigh = v ? 10 : 20;
    const float* im0 = im + (size_t)b * 3 * HWP;
    const float scale = dw * (1.0f / 31.0f);
    float rf0 = (im0[p] + 1.f) * 0.5f;
    float rf1 = (im0[HWP + p] + 1.f) * 0.5f;
    float rf2 = (im0[2 * HWP + p] + 1.f) * 0.5f;
    float rx = (float)(p & 31) * scale;
    float ry = (float)(p >> 5) * scale;
    unsigned long long key[16];
    #pragma unroll
    for (int e = 0; e < 16; ++e) {
        int q = e * 64 + lane;
        float f0 = (im0[q] + 1.f) * 0.5f - rf0;
        float f1 = (im0[HWP + q] + 1.f) * 0.5f - rf1;
        float f2 = (im0[2 * HWP + q] + 1.f) * 0.5f - rf2;
        float fx = (float)(q & 31) * scale - rx;
        float fy = (float)(q >> 5) * scale - ry;
        float d = f0 * f0 + f1 * f1 + f2 * f2 + fx * fx + fy * fy;
        unsigned int db = __float_as_uint(d);
        key[e] = (q == p) ? ~0ull : ((((unsigned long long)db) << 10) | (unsigned int)q);
    }
    unsigned int selmask = 0;
    for (int it = 0; it < kneigh; ++it) {
        unsigned long long m = key[0];
        #pragma unroll
        for (int e = 1; e < 16; ++e) m = (key[e] < m) ? key[e] : m;
        #pragma unroll
        for (int off = 1; off < 64; off <<= 1) {
            unsigned long long o = __shfl_xor((unsigned long long)m, off, 64);
            m = (o < m) ? o : m;
        }
        int q = (int)(m & 1023u);
        if ((q & 63) == lane) {
            int e = q >> 6;
            selmask |= 1u << e;
            key[e] = ~0ull;
        }
    }
    unsigned char* dst = (v ? res10 : res20) + ((size_t)(b * HWP + p)) * HWP;
    #pragma unroll
    for (int e = 0; e < 16; ++e) dst[e * 64 + lane] = (unsigned char)((selmask >> e) & 1u);
}

// ---------------- A = relu(offdiag(FFn FFn^T)) + 0.1*blockdiag(kNN)  [MFMA 128x128 tile] ----------------
__global__ __launch_bounds__(256, 2) void k_gram(const unsigned short* __restrict__ FFnb,
                                                 const unsigned char* __restrict__ res20,
                                                 const unsigned char* __restrict__ res10,
                                                 unsigned short* __restrict__ A) {
    __shared__ __align__(16) unsigned short As[128 * 64];
    __shared__ __align__(16) unsigned short Bs[128 * 64];
    int fid = blockIdx.y * gridDim.x + blockIdx.x;
    int s = (fid & 7) * 512 + (fid >> 3);          // XCD swizzle, 4096 % 8 == 0
    const int ti = s >> 6, tj = s & 63;
    const int row0 = ti * 128, col0 = tj * 128;
    const int tid = threadIdx.x, l = tid & 63, wid = tid >> 6;
    const int wr = (wid >> 1) * 64, wc = (wid & 1) * 64;
    const int arl = wr + (l & 15), brl = wc + (l & 15), lhi = l >> 4;
    f32x4 z = {0.f, 0.f, 0.f, 0.f};
    f32x4 acc[4][4];
    #pragma unroll
    for (int m = 0; m < 4; ++m)
        #pragma unroll
        for (int n = 0; n < 4; ++n) acc[m][n] = z;

    for (int k0 = 0; k0 < CC; k0 += 64) {
        stage_tile(FFnb + (long)row0 * CC, CC, k0, As);
        stage_tile(FFnb + (long)col0 * CC, CC, k0, Bs);
        __syncthreads();
        gemm_step(As, Bs, arl, brl, lhi, acc);
        __syncthreads();
    }
    const bool diagBlk = (row0 >> 10) == (col0 >> 10);
    const long mbase = ((long)(row0 >> 10)) << 20;
    #pragma unroll
    for (int m = 0; m < 4; ++m) {
        #pragma unroll
        for (int n = 0; n < 4; ++n) {
            #pragma unroll
            for (int r = 0; r < 4; ++r) {
                int gi = row0 + wr + m * 16 + lhi * 4 + r;
                int gj = col0 + wc + n * 16 + (l & 15);
                float vv = acc[m][n][r];
                vv = (gi == gj) ? 0.f : fmaxf(vv, 0.f);
                if (diagBlk) {
                    int li = gi & 1023, lj = gj & 1023;
                    unsigned char mm = (unsigned char)(
                        (res20[mbase + (long)li * HWP + lj] & res20[mbase + (long)lj * HWP + li]) |
                        (res10[mbase + (long)li * HWP + lj] & res10[mbase + (long)lj * HWP + li]));
                    vv += 0.1f * (float)mm;
                }
                A[(long)gi * NN + gj] = f2bf(vv);
            }
        }
    }
}

// ---------------- rowsum of bf16 A ----------------
__global__ __launch_bounds__(256) void k_rowsum(const unsigned short* __restrict__ A,
                                                float* __restrict__ rowsum) {
    const int row = blockIdx.x;
    const unsigned short* src = A + (long)row * NN;
    const int tid = threadIdx.x;
    float s = 0.f;
    #pragma unroll
    for (int i = 0; i < 4; ++i) {
        bf16x8 v = *(const bf16x8*)(src + (size_t)(i * 256 + tid) * 8);
        #pragma unroll
        for (int e = 0; e < 8; ++e) s += bf2f((unsigned short)v[e]);
    }
    #pragma unroll
    for (int off = 32; off > 0; off >>= 1) s += __shfl_down(s, off, 64);
    __shared__ float ls[4];
    if ((tid & 63) == 0) ls[tid >> 6] = s;
    __syncthreads();
    if (tid == 0) rowsum[row] = ls[0] + ls[1] + ls[2] + ls[3];
}

// ---------------- D = rsqrt(rowsum/(N-1)) ----------------
__global__ __launch_bounds__(256) void k_d(const float* __restrict__ rowsum,
                                           float* __restrict__ Dv) {
    int i = blockIdx.x * 256 + threadIdx.x;
    Dv[i] = 1.0f / sqrtf(rowsum[i] * (1.0f / 8191.0f));
}

// ---------------- Psi transposes via LDS tile: PaT=(T/N)Psi^T, PsT=PaT*Dv (bf16) ----------------
__global__ __launch_bounds__(256) void k_psiT(const float* __restrict__ Psi,
                                              const float* __restrict__ Dv,
                                              unsigned short* __restrict__ PaT,
                                              unsigned short* __restrict__ PsT) {
    __shared__ unsigned short tile[128][72];
    __shared__ float Dvs[64];
    const int j0 = blockIdx.x * 64;    // 128 blocks
    const int n0 = blockIdx.y * 128;   // 4 blocks
    const int t = threadIdx.x;
    if (t < 64) Dvs[t] = Dv[j0 + t];
    #pragma unroll
    for (int i = 0; i < 8; ++i) {
        int jl = i * 8 + (t >> 5);
        int c4 = (t & 31) * 4;
        float4 vv = *(const float4*)(Psi + (size_t)(j0 + jl) * KD + n0 + c4);
        tile[c4 + 0][jl] = f2bf(vv.x * T_OVER_N);
        tile[c4 + 1][jl] = f2bf(vv.y * T_OVER_N);
        tile[c4 + 2][jl] = f2bf(vv.z * T_OVER_N);
        tile[c4 + 3][jl] = f2bf(vv.w * T_OVER_N);
    }
    __syncthreads();
    const int nl = t >> 1;
    const int jh = (t & 1) * 32;
    unsigned short pa[32], ps[32];
    #pragma unroll
    for (int jj = 0; jj < 32; ++jj) {
        unsigned short u = tile[nl][jh + jj];
        pa[jj] = u;
        ps[jj] = f2bf(bf2f(u) * Dvs[jh + jj]);
    }
    unsigned short* dpa = PaT + (size_t)(n0 + nl) * NN + j0 + jh;
    unsigned short* dps = PsT + (size_t)(n0 + nl) * NN + j0 + jh;
    #pragma unroll
    for (int c = 0; c < 4; ++c) {
        *(bf16x8*)(dpa + c * 8) = *(const bf16x8*)(pa + c * 8);
        *(bf16x8*)(dps + c * 8) = *(const bf16x8*)(ps + c * 8);
    }
}

// ---------------- YT[n][i] = Dv[i] * sum_j PsT[n][j] * A[i][j]   (A symmetric) ----------------
__global__ __launch_bounds__(256, 2) void k_yt(const unsigned short* __restrict__ PsT,
                                               const unsigned short* __restrict__ A,
                                               const float* __restrict__ Dv,
                                               unsigned short* __restrict__ YT) {
    __shared__ __align__(16) unsigned short As[128 * 64];
    __shared__ __align__(16) unsigned short Bs[128 * 64];
    int s = (blockIdx.x & 7) * 32 + (blockIdx.x >> 3);   // XCD swizzle, 256 % 8 == 0
    const int nt = s >> 6, it = s & 63;
    const int row0 = nt * 128, col0 = it * 128;
    const int tid = threadIdx.x, l = tid & 63, wid = tid >> 6;
    const int wr = (wid >> 1) * 64, wc = (wid & 1) * 64;
    const int arl = wr + (l & 15), brl = wc + (l & 15), lhi = l >> 4;
    f32x4 z = {0.f, 0.f, 0.f, 0.f};
    f32x4 acc[4][4];
    #pragma unroll
    for (int m = 0; m < 4; ++m)
        #pragma unroll
        for (int n = 0; n < 4; ++n) acc[m][n] = z;

    for (int k0 = 0; k0 < NN; k0 += 64) {
        stage_tile(PsT + (long)row0 * NN, NN, k0, As);
        stage_tile(A + (long)col0 * NN, NN, k0, Bs);
        __syncthreads();
        gemm_step(As, Bs, arl, brl, lhi, acc);
        __syncthreads();
    }
    #pragma unroll
    for (int m = 0; m < 4; ++m) {
        #pragma unroll
        for (int n = 0; n < 4; ++n) {
            #pragma unroll
            for (int r = 0; r < 4; ++r) {
                int gi = row0 + wr + m * 16 + lhi * 4 + r;
                int gj = col0 + wc + n * 16 + (l & 15);
                YT[(long)gi * NN + gj] = f2bf(acc[m][n][r] * Dv[gj]);
            }
        }
    }
}

// ---------------- R += PaT-tile * YT-tile^T (K-split, atomic fp32) ----------------
__global__ __launch_bounds__(256, 2) void k_r(const unsigned short* __restrict__ PaT,
                                              const unsigned short* __restrict__ YT,
                                              float* __restrict__ R) {
    const int t2 = blockIdx.x, t1 = blockIdx.y, kz = blockIdx.z;
    if (t1 > t2) return;
    __shared__ __align__(16) unsigned short As[128 * 64];
    __shared__ __align__(16) unsigned short Bs[128 * 64];
    const int row0 = t1 * 128, col0 = t2 * 128;
    const int tid = threadIdx.x, l = tid & 63, wid = tid >> 6;
    const int wr = (wid >> 1) * 64, wc = (wid & 1) * 64;
    const int arl = wr + (l & 15), brl = wc + (l & 15), lhi = l >> 4;
    f32x4 z = {0.f, 0.f, 0.f, 0.f};
    f32x4 acc[4][4];
    #pragma unroll
    for (int m = 0; m < 4; ++m)
        #pragma unroll
        for (int n = 0; n < 4; ++n) acc[m][n] = z;

    const int kbeg = kz * 2048, kend = kbeg + 2048;
    for (int k0 = kbeg; k0 < kend; k0 += 64) {
        stage_tile(PaT + (long)row0 * NN, NN, k0, As);
        stage_tile(YT + (long)col0 * NN, NN, k0, Bs);
        __syncthreads();
        gemm_step(As, Bs, arl, brl, lhi, acc);
        __syncthreads();
    }
    #pragma unroll
    for (int m = 0; m < 4; ++m) {
        #pragma unroll
        for (int n = 0; n < 4; ++n) {
            #pragma unroll
            for (int r = 0; r < 4; ++r) {
                int gk1 = row0 + wr + m * 16 + lhi * 4 + r;
                int gk2 = col0 + wc + n * 16 + (l & 15);
                atomicAdd(&R[(long)gk1 * KD + gk2], acc[m][n][r]);
            }
        }
    }
}

// ---------------- trace & triu^2 reduction of R ----------------
__global__ __launch_bounds__(256) void k_tri(const float* __restrict__ R,
                                             float* __restrict__ acc2) {
    float tr = 0.f, rg = 0.f;
    for (int idx = blockIdx.x * 256 + threadIdx.x; idx < KD * KD; idx += 64 * 256) {
        int k1 = idx >> 9, k2 = idx & 511;
        float v = R[idx];
        if (k1 == k2) tr += v;
        else if (k1 < k2) rg += v * v;
    }
    #pragma unroll
    for (int off = 32; off > 0; off >>= 1) {
        tr += __shfl_down(tr, off, 64);
        rg += __shfl_down(rg, off, 64);
    }
    __shared__ float lt[4], lr[4];
    int tid = threadIdx.x;
    if ((tid & 63) == 0) { lt[tid >> 6] = tr; lr[tid >> 6] = rg; }
    __syncthreads();
    if (tid == 0) {
        atomicAdd(&acc2[0], lt[0] + lt[1] + lt[2] + lt[3]);
        atomicAdd(&acc2[1], lr[0] + lr[1] + lr[2] + lr[3]);
    }
}

// ---------------- finalize ----------------
__global__ void k_fin(const float* __restrict__ acc2, float* __restrict__ out) {
    out[0] = -acc2[0];
    out[1] = 0.05f * acc2[1];
}

extern "C" void kernel_launch(void* const* d_in, const int* in_sizes, int n_in,
                              void* d_out, int out_size, void* d_ws, size_t ws_size,
                              hipStream_t stream) {
    const float* FF  = (const float*)d_in[0];
    const float* Psi = (const float*)d_in[1];
    const float* im  = (const float*)d_in[2];
    float* out = (float*)d_out;
    char* ws = (char*)d_ws;
    size_t off = 0;
    auto alloc = [&](size_t bytes) {
        size_t o = off;
        off += (bytes + 255) & ~(size_t)255;
        return o;
    };
    unsigned short* FFnb  = (unsigned short*)(ws + alloc((size_t)NN * CC * 2));
    unsigned char* res20  = (unsigned char*)(ws + alloc((size_t)8 * HWP * HWP));
    unsigned char* res10  = (unsigned char*)(ws + alloc((size_t)8 * HWP * HWP));
    float* rowsum         = (float*)(ws + alloc((size_t)NN * 4));
    float* Dv             = (float*)(ws + alloc((size_t)NN * 4));
    unsigned short* PaT   = (unsigned short*)(ws + alloc((size_t)KD * NN * 2));
    unsigned short* PsT   = (unsigned short*)(ws + alloc((size_t)KD * NN * 2));
    unsigned short* YT    = (unsigned short*)(ws + alloc((size_t)KD * NN * 2));
    float* R              = (float*)(ws + alloc((size_t)KD * KD * 4));
    float* acc2           = (float*)(ws + alloc(256));
    unsigned short* A     = (unsigned short*)(ws + alloc((size_t)NN * NN * 2));

    hipMemsetAsync(R, 0, (size_t)KD * KD * 4, stream);
    hipMemsetAsync(acc2, 0, 8, stream);

    k_normalize<<<NN, 128, 0, stream>>>(FF, FFnb);
    k_knn<<<4096, 256, 0, stream>>>(im, res20, res10);
    k_gram<<<dim3(64, 64), 256, 0, stream>>>(FFnb, res20, res10, A);
    k_rowsum<<<NN, 256, 0, stream>>>(A, rowsum);
    k_d<<<NN / 256, 256, 0, stream>>>(rowsum, Dv);
    k_psiT<<<dim3(128, 4), 256, 0, stream>>>(Psi, Dv, PaT, PsT);
    k_yt<<<256, 256, 0, stream>>>(PsT, A, Dv, YT);
    k_r<<<dim3(4, 4, 4), 256, 0, stream>>>(PaT, YT, R);
    k_tri<<<64, 256, 0, stream>>>(R, acc2);
    k_fin<<<1, 1, 0, stream>>>(acc2, out);
}

// Round 6
// 405.364 us; speedup vs baseline: 5.1762x; 1.0081x over previous
//
#include <hip/hip_runtime.h>
#include <hip/hip_bf16.h>

#define NN 8192
#define CC 384
#define KD 512
#define HWP 1024

typedef __attribute__((ext_vector_type(8))) short bf16x8;
typedef __attribute__((ext_vector_type(4))) float f32x4;

static constexpr float T_OVER_N = 10.0f / 8192.0f;

__device__ __forceinline__ float bf2f(unsigned short u) {
    union { unsigned int i; float f; } x;
    x.i = ((unsigned int)u) << 16;
    return x.f;
}
__device__ __forceinline__ unsigned short f2bf(float f) {
    __hip_bfloat16 h = __float2bfloat16(f);
    unsigned short u;
    __builtin_memcpy(&u, &h, sizeof(u));
    return u;
}

// ---------- 128x64 bf16 tile staging via global_load_lds (16B), source-side XOR swizzle ----------
__device__ __forceinline__ void stage_tile(const unsigned short* __restrict__ src, long ld,
                                           int k0, unsigned short* lds) {
    const int t = threadIdx.x;  // blockDim == 256
    #pragma unroll
    for (int i = 0; i < 4; ++i) {
        int slot = i * 256 + t;          // 16B slot 0..1023 (8 per row)
        int row = slot >> 3;
        int cl = (slot & 7) ^ (row & 7); // logical chunk for this stored slot
        const unsigned short* g = src + (long)row * ld + k0 + cl * 8;
        __builtin_amdgcn_global_load_lds((const __attribute__((address_space(1))) void*)g,
                                         (__attribute__((address_space(3))) void*)(lds + (size_t)slot * 8),
                                         16, 0, 0);
    }
}

__device__ __forceinline__ bf16x8 read_frag(const unsigned short* lds, int r, int chunk) {
    int byte = (r << 7) + (((chunk ^ r) & 7) << 4) + ((chunk & ~7) << 4);
    return *(const bf16x8*)((const char*)lds + byte);
}

__device__ __forceinline__ void gemm_step(const unsigned short* As, const unsigned short* Bs,
                                          int arl, int brl, int lhi, f32x4 (&acc)[4][4]) {
    #pragma unroll
    for (int ks = 0; ks < 2; ++ks) {
        bf16x8 a[4], b[4];
        #pragma unroll
        for (int m = 0; m < 4; ++m) a[m] = read_frag(As, arl + m * 16, ks * 4 + lhi);
        #pragma unroll
        for (int n = 0; n < 4; ++n) b[n] = read_frag(Bs, brl + n * 16, ks * 4 + lhi);
        #pragma unroll
        for (int m = 0; m < 4; ++m)
            #pragma unroll
            for (int n = 0; n < 4; ++n)
                acc[m][n] = __builtin_amdgcn_mfma_f32_16x16x32_bf16(a[m], b[n], acc[m][n], 0, 0, 0);
    }
}

// ---------------- row-normalize FF -> bf16 FFnb ----------------
__global__ __launch_bounds__(128) void k_normalize(const float* __restrict__ FF,
                                                   unsigned short* __restrict__ FFnb) {
    int row = blockIdx.x;
    int tid = threadIdx.x;
    const float* src = FF + (size_t)row * CC;
    float v0 = src[tid], v1 = src[tid + 128], v2 = src[tid + 256];
    float s = v0 * v0 + v1 * v1 + v2 * v2;
    #pragma unroll
    for (int off = 32; off > 0; off >>= 1) s += __shfl_down(s, off, 64);
    __shared__ float ls[2];
    if ((tid & 63) == 0) ls[tid >> 6] = s;
    __syncthreads();
    float inv = 1.0f / sqrtf(ls[0] + ls[1]);
    unsigned short* dst = FFnb + (size_t)row * CC;
    dst[tid] = f2bf(v0 * inv);
    dst[tid + 128] = f2bf(v1 * inv);
    dst[tid + 256] = f2bf(v2 * inv);
}

// ---------------- kNN: one wave per (pixel-row, image, variant) task ----------------
__global__ __launch_bounds__(256) void k_knn(const float* __restrict__ im,
                                             unsigned char* __restrict__ res20,
                                             unsigned char* __restrict__ res10) {
    const int lane = threadIdx.x & 63;
    const int id = blockIdx.x * 4 + (threadIdx.x >> 6);   // 0..16383
    const int v = id & 1;
    const int rest = id >> 1;
    const int p = rest & 1023;
    const int b = rest >> 10;
    const float dw = v ? 0.1f : 2.0f;
    const int kneigh = v ? 10 : 20;
    const float* im0 = im + (size_t)b * 3 * HWP;
    const float scale = dw * (1.0f / 31.0f);
    float rf0 = (im0[p] + 1.f) * 0.5f;
    float rf1 = (im0[HWP + p] + 1.f) * 0.5f;
    float rf2 = (im0[2 * HWP + p] + 1.f) * 0.5f;
    float rx = (float)(p & 31) * scale;
    float ry = (float)(p >> 5) * scale;
    unsigned long long key[16];
    #pragma unroll
    for (int e = 0; e < 16; ++e) {
        int q = e * 64 + lane;
        float f0 = (im0[q] + 1.f) * 0.5f - rf0;
        float f1 = (im0[HWP + q] + 1.f) * 0.5f - rf1;
        float f2 = (im0[2 * HWP + q] + 1.f) * 0.5f - rf2;
        float fx = (float)(q & 31) * scale - rx;
        float fy = (float)(q >> 5) * scale - ry;
        float d = f0 * f0 + f1 * f1 + f2 * f2 + fx * fx + fy * fy;
        unsigned int db = __float_as_uint(d);
        key[e] = (q == p) ? ~0ull : ((((unsigned long long)db) << 10) | (unsigned int)q);
    }
    unsigned int selmask = 0;
    for (int it = 0; it < kneigh; ++it) {
        unsigned long long m = key[0];
        #pragma unroll
        for (int e = 1; e < 16; ++e) m = (key[e] < m) ? key[e] : m;
        #pragma unroll
        for (int off = 1; off < 64; off <<= 1) {
            unsigned long long o = __shfl_xor((unsigned long long)m, off, 64);
            m = (o < m) ? o : m;
        }
        int q = (int)(m & 1023u);
        if ((q & 63) == lane) {
            int e = q >> 6;
            selmask |= 1u << e;
            key[e] = ~0ull;
        }
    }
    unsigned char* dst = (v ? res10 : res20) + ((size_t)(b * HWP + p)) * HWP;
    #pragma unroll
    for (int e = 0; e < 16; ++e) dst[e * 64 + lane] = (unsigned char)((selmask >> e) & 1u);
}

// ---------------- A = relu(offdiag(FFn FFn^T)) + 0.1*blockdiag(kNN); fused rowsum ----------------
__global__ __launch_bounds__(256, 4) void k_gram(const unsigned short* __restrict__ FFnb,
                                                 const unsigned char* __restrict__ res20,
                                                 const unsigned char* __restrict__ res10,
                                                 unsigned short* __restrict__ A,
                                                 float* __restrict__ rowsum) {
    __shared__ __align__(16) unsigned short As[128 * 64];
    __shared__ __align__(16) unsigned short Bs[128 * 64];
    int fid = blockIdx.y * gridDim.x + blockIdx.x;
    int s = (fid & 7) * 512 + (fid >> 3);          // XCD swizzle, 4096 % 8 == 0
    const int ti = s >> 6, tj = s & 63;
    const int row0 = ti * 128, col0 = tj * 128;
    const int tid = threadIdx.x, l = tid & 63, wid = tid >> 6;
    const int wr = (wid >> 1) * 64, wc = (wid & 1) * 64;
    const int arl = wr + (l & 15), brl = wc + (l & 15), lhi = l >> 4;
    f32x4 z = {0.f, 0.f, 0.f, 0.f};
    f32x4 acc[4][4];
    #pragma unroll
    for (int m = 0; m < 4; ++m)
        #pragma unroll
        for (int n = 0; n < 4; ++n) acc[m][n] = z;

    for (int k0 = 0; k0 < CC; k0 += 64) {
        stage_tile(FFnb + (long)row0 * CC, CC, k0, As);
        stage_tile(FFnb + (long)col0 * CC, CC, k0, Bs);
        __syncthreads();
        gemm_step(As, Bs, arl, brl, lhi, acc);
        __syncthreads();
    }
    const bool diagBlk = (row0 >> 10) == (col0 >> 10);
    const long mbase = ((long)(row0 >> 10)) << 20;
    float rs[4][4];
    #pragma unroll
    for (int m = 0; m < 4; ++m)
        #pragma unroll
        for (int r = 0; r < 4; ++r) rs[m][r] = 0.f;
    #pragma unroll
    for (int m = 0; m < 4; ++m) {
        #pragma unroll
        for (int n = 0; n < 4; ++n) {
            #pragma unroll
            for (int r = 0; r < 4; ++r) {
                int gi = row0 + wr + m * 16 + lhi * 4 + r;
                int gj = col0 + wc + n * 16 + (l & 15);
                float vv = acc[m][n][r];
                vv = (gi == gj) ? 0.f : fmaxf(vv, 0.f);
                if (diagBlk) {
                    int li = gi & 1023, lj = gj & 1023;
                    unsigned char mm = (unsigned char)(
                        (res20[mbase + (long)li * HWP + lj] & res20[mbase + (long)lj * HWP + li]) |
                        (res10[mbase + (long)li * HWP + lj] & res10[mbase + (long)lj * HWP + li]));
                    vv += 0.1f * (float)mm;
                }
                A[(long)gi * NN + gj] = f2bf(vv);
                rs[m][r] += vv;
            }
        }
    }
    // rowsum: reduce each rs[m][r] across the 16 lanes sharing (lhi, m, r)
    #pragma unroll
    for (int m = 0; m < 4; ++m)
        #pragma unroll
        for (int r = 0; r < 4; ++r) {
            float p = rs[m][r];
            #pragma unroll
            for (int off = 1; off < 16; off <<= 1) p += __shfl_xor(p, off, 64);
            if ((l & 15) == 0) atomicAdd(&rowsum[row0 + wr + m * 16 + lhi * 4 + r], p);
        }
}

// ---------------- D = rsqrt(rowsum/(N-1)) ----------------
__global__ __launch_bounds__(256) void k_d(const float* __restrict__ rowsum,
                                           float* __restrict__ Dv) {
    int i = blockIdx.x * 256 + threadIdx.x;
    Dv[i] = 1.0f / sqrtf(rowsum[i] * (1.0f / 8191.0f));
}

// ---------------- Psi transposes via LDS tile: PaT=(T/N)Psi^T, PsT=PaT*Dv (bf16) ----------------
__global__ __launch_bounds__(256) void k_psiT(const float* __restrict__ Psi,
                                              const float* __restrict__ Dv,
                                              unsigned short* __restrict__ PaT,
                                              unsigned short* __restrict__ PsT) {
    __shared__ unsigned short tile[128][72];
    __shared__ float Dvs[64];
    const int j0 = blockIdx.x * 64;    // 128 blocks
    const int n0 = blockIdx.y * 128;   // 4 blocks
    const int t = threadIdx.x;
    if (t < 64) Dvs[t] = Dv[j0 + t];
    #pragma unroll
    for (int i = 0; i < 8; ++i) {
        int jl = i * 8 + (t >> 5);
        int c4 = (t & 31) * 4;
        float4 vv = *(const float4*)(Psi + (size_t)(j0 + jl) * KD + n0 + c4);
        tile[c4 + 0][jl] = f2bf(vv.x * T_OVER_N);
        tile[c4 + 1][jl] = f2bf(vv.y * T_OVER_N);
        tile[c4 + 2][jl] = f2bf(vv.z * T_OVER_N);
        tile[c4 + 3][jl] = f2bf(vv.w * T_OVER_N);
    }
    __syncthreads();
    const int nl = t >> 1;
    const int jh = (t & 1) * 32;
    unsigned short pa[32], ps[32];
    #pragma unroll
    for (int jj = 0; jj < 32; ++jj) {
        unsigned short u = tile[nl][jh + jj];
        pa[jj] = u;
        ps[jj] = f2bf(bf2f(u) * Dvs[jh + jj]);
    }
    unsigned short* dpa = PaT + (size_t)(n0 + nl) * NN + j0 + jh;
    unsigned short* dps = PsT + (size_t)(n0 + nl) * NN + j0 + jh;
    #pragma unroll
    for (int c = 0; c < 4; ++c) {
        *(bf16x8*)(dpa + c * 8) = *(const bf16x8*)(pa + c * 8);
        *(bf16x8*)(dps + c * 8) = *(const bf16x8*)(ps + c * 8);
    }
}

// ---------------- YTacc[n][i] += sum_{k-chunk} PsT[n][k] * A[i][k]  (K-split x4, fp32 atomics) ----------------
__global__ __launch_bounds__(256, 4) void k_ytks(const unsigned short* __restrict__ PsT,
                                                 const unsigned short* __restrict__ A,
                                                 float* __restrict__ YTacc) {
    __shared__ __align__(16) unsigned short As[128 * 64];
    __shared__ __align__(16) unsigned short Bs[128 * 64];
    const int b = blockIdx.x;            // 1024 blocks
    const int xcd = b & 7, slot = b >> 3;
    const int nt = slot & 3, g = slot >> 2;
    const int pair = xcd * 32 + g;       // 256 (kz,it) pairs
    const int it = pair & 63, kz = pair >> 6;
    const int row0 = nt * 128, col0 = it * 128;
    const int tid = threadIdx.x, l = tid & 63, wid = tid >> 6;
    const int wr = (wid >> 1) * 64, wc = (wid & 1) * 64;
    const int arl = wr + (l & 15), brl = wc + (l & 15), lhi = l >> 4;
    f32x4 z = {0.f, 0.f, 0.f, 0.f};
    f32x4 acc[4][4];
    #pragma unroll
    for (int m = 0; m < 4; ++m)
        #pragma unroll
        for (int n = 0; n < 4; ++n) acc[m][n] = z;

    const int kbeg = kz * 2048;
    for (int k0 = kbeg; k0 < kbeg + 2048; k0 += 64) {
        stage_tile(PsT + (long)row0 * NN, NN, k0, As);
        stage_tile(A + (long)col0 * NN, NN, k0, Bs);
        __syncthreads();
        gemm_step(As, Bs, arl, brl, lhi, acc);
        __syncthreads();
    }
    #pragma unroll
    for (int m = 0; m < 4; ++m) {
        #pragma unroll
        for (int n = 0; n < 4; ++n) {
            #pragma unroll
            for (int r = 0; r < 4; ++r) {
                int gi = row0 + wr + m * 16 + lhi * 4 + r;
                int gj = col0 + wc + n * 16 + (l & 15);
                atomicAdd(&YTacc[(long)gi * NN + gj], acc[m][n][r]);
            }
        }
    }
}

// ---------------- YT = bf16(YTacc * Dv[col]) ----------------
__global__ __launch_bounds__(256) void k_ytfin(const float* __restrict__ YTacc,
                                               const float* __restrict__ Dv,
                                               unsigned short* __restrict__ YT) {
    long idx8 = ((long)blockIdx.x * 256 + threadIdx.x) * 8;
    int i = (int)(idx8 & (NN - 1));
    float4 a0 = *(const float4*)(YTacc + idx8);
    float4 a1 = *(const float4*)(YTacc + idx8 + 4);
    float4 d0 = *(const float4*)(Dv + i);
    float4 d1 = *(const float4*)(Dv + i + 4);
    bf16x8 o;
    o[0] = (short)f2bf(a0.x * d0.x); o[1] = (short)f2bf(a0.y * d0.y);
    o[2] = (short)f2bf(a0.z * d0.z); o[3] = (short)f2bf(a0.w * d0.w);
    o[4] = (short)f2bf(a1.x * d1.x); o[5] = (short)f2bf(a1.y * d1.y);
    o[6] = (short)f2bf(a1.z * d1.z); o[7] = (short)f2bf(a1.w * d1.w);
    *(bf16x8*)(YT + idx8) = o;
}

// ---------------- R += PaT-tile * YT-tile^T (dense triangular grid, K-split x8 of 1024) ----------------
__global__ __launch_bounds__(256, 2) void k_r(const unsigned short* __restrict__ PaT,
                                              const unsigned short* __restrict__ YT,
                                              float* __restrict__ R) {
    static const int t1tab[10] = {0,0,0,0,1,1,1,2,2,3};
    static const int t2tab[10] = {0,1,2,3,1,2,3,2,3,3};
    const int t1 = t1tab[blockIdx.x], t2 = t2tab[blockIdx.x], kz = blockIdx.y;
    __shared__ __align__(16) unsigned short As[128 * 64];
    __shared__ __align__(16) unsigned short Bs[128 * 64];
    const int row0 = t1 * 128, col0 = t2 * 128;
    const int tid = threadIdx.x, l = tid & 63, wid = tid >> 6;
    const int wr = (wid >> 1) * 64, wc = (wid & 1) * 64;
    const int arl = wr + (l & 15), brl = wc + (l & 15), lhi = l >> 4;
    f32x4 z = {0.f, 0.f, 0.f, 0.f};
    f32x4 acc[4][4];
    #pragma unroll
    for (int m = 0; m < 4; ++m)
        #pragma unroll
        for (int n = 0; n < 4; ++n) acc[m][n] = z;

    const int kbeg = kz * 1024;               // 8 x 1024 = 8192 (round-5 bug: was kz*512)
    for (int k0 = kbeg; k0 < kbeg + 1024; k0 += 64) {
        stage_tile(PaT + (long)row0 * NN, NN, k0, As);
        stage_tile(YT + (long)col0 * NN, NN, k0, Bs);
        __syncthreads();
        gemm_step(As, Bs, arl, brl, lhi, acc);
        __syncthreads();
    }
    #pragma unroll
    for (int m = 0; m < 4; ++m) {
        #pragma unroll
        for (int n = 0; n < 4; ++n) {
            #pragma unroll
            for (int r = 0; r < 4; ++r) {
                int gk1 = row0 + wr + m * 16 + lhi * 4 + r;
                int gk2 = col0 + wc + n * 16 + (l & 15);
                atomicAdd(&R[(long)gk1 * KD + gk2], acc[m][n][r]);
            }
        }
    }
}

// ---------------- trace & triu^2 reduction of R ----------------
__global__ __launch_bounds__(256) void k_tri(const float* __restrict__ R,
                                             float* __restrict__ acc2) {
    float tr = 0.f, rg = 0.f;
    for (int idx = blockIdx.x * 256 + threadIdx.x; idx < KD * KD; idx += 64 * 256) {
        int k1 = idx >> 9, k2 = idx & 511;
        float v = R[idx];
        if (k1 == k2) tr += v;
        else if (k1 < k2) rg += v * v;
    }
    #pragma unroll
    for (int off = 32; off > 0; off >>= 1) {
        tr += __shfl_down(tr, off, 64);
        rg += __shfl_down(rg, off, 64);
    }
    __shared__ float lt[4], lr[4];
    int tid = threadIdx.x;
    if ((tid & 63) == 0) { lt[tid >> 6] = tr; lr[tid >> 6] = rg; }
    __syncthreads();
    if (tid == 0) {
        atomicAdd(&acc2[0], lt[0] + lt[1] + lt[2] + lt[3]);
        atomicAdd(&acc2[1], lr[0] + lr[1] + lr[2] + lr[3]);
    }
}

// ---------------- finalize ----------------
__global__ void k_fin(const float* __restrict__ acc2, float* __restrict__ out) {
    out[0] = -acc2[0];
    out[1] = 0.05f * acc2[1];
}

extern "C" void kernel_launch(void* const* d_in, const int* in_sizes, int n_in,
                              void* d_out, int out_size, void* d_ws, size_t ws_size,
                              hipStream_t stream) {
    const float* FF  = (const float*)d_in[0];
    const float* Psi = (const float*)d_in[1];
    const float* im  = (const float*)d_in[2];
    float* out = (float*)d_out;
    char* ws = (char*)d_ws;
    size_t off = 0;
    auto alloc = [&](size_t bytes) {
        size_t o = off;
        off += (bytes + 255) & ~(size_t)255;
        return o;
    };
    unsigned short* FFnb  = (unsigned short*)(ws + alloc((size_t)NN * CC * 2));
    unsigned char* res20  = (unsigned char*)(ws + alloc((size_t)8 * HWP * HWP));
    unsigned char* res10  = (unsigned char*)(ws + alloc((size_t)8 * HWP * HWP));
    float* rowsum         = (float*)(ws + alloc((size_t)NN * 4));
    float* Dv             = (float*)(ws + alloc((size_t)NN * 4));
    unsigned short* PaT   = (unsigned short*)(ws + alloc((size_t)KD * NN * 2));
    unsigned short* PsT   = (unsigned short*)(ws + alloc((size_t)KD * NN * 2));
    unsigned short* YT    = (unsigned short*)(ws + alloc((size_t)KD * NN * 2));
    float* YTacc          = (float*)(ws + alloc((size_t)KD * NN * 4));
    float* R              = (float*)(ws + alloc((size_t)KD * KD * 4));
    float* acc2           = (float*)(ws + alloc(256));
    unsigned short* A     = (unsigned short*)(ws + alloc((size_t)NN * NN * 2));

    hipMemsetAsync(rowsum, 0, (size_t)NN * 4, stream);
    hipMemsetAsync(YTacc, 0, (size_t)KD * NN * 4, stream);
    hipMemsetAsync(R, 0, (size_t)KD * KD * 4, stream);
    hipMemsetAsync(acc2, 0, 8, stream);

    k_normalize<<<NN, 128, 0, stream>>>(FF, FFnb);
    k_knn<<<4096, 256, 0, stream>>>(im, res20, res10);
    k_gram<<<dim3(64, 64), 256, 0, stream>>>(FFnb, res20, res10, A, rowsum);
    k_d<<<NN / 256, 256, 0, stream>>>(rowsum, Dv);
    k_psiT<<<dim3(128, 4), 256, 0, stream>>>(Psi, Dv, PaT, PsT);
    k_ytks<<<1024, 256, 0, stream>>>(PsT, A, YTacc);
    k_ytfin<<<(KD * NN) / (256 * 8), 256, 0, stream>>>(YTacc, Dv, YT);
    k_r<<<dim3(10, 8), 256, 0, stream>>>(PaT, YT, R);
    k_tri<<<64, 256, 0, stream>>>(R, acc2);
    k_fin<<<1, 1, 0, stream>>>(acc2, out);
}

// Round 7
// 351.831 us; speedup vs baseline: 5.9637x; 1.1522x over previous
//
#include <hip/hip_runtime.h>
#include <hip/hip_bf16.h>

#define NN 8192
#define CC 384
#define KD 512
#define HWP 1024

typedef __attribute__((ext_vector_type(8))) short bf16x8;
typedef __attribute__((ext_vector_type(4))) float f32x4;

static constexpr float T_OVER_N = 10.0f / 8192.0f;

__device__ __forceinline__ float bf2f(unsigned short u) {
    union { unsigned int i; float f; } x;
    x.i = ((unsigned int)u) << 16;
    return x.f;
}
__device__ __forceinline__ unsigned short f2bf(float f) {
    __hip_bfloat16 h = __float2bfloat16(f);
    unsigned short u;
    __builtin_memcpy(&u, &h, sizeof(u));
    return u;
}

// ---------- 128x64 bf16 tile staging via global_load_lds (16B), source-side XOR swizzle ----------
__device__ __forceinline__ void stage_tile(const unsigned short* __restrict__ src, long ld,
                                           int k0, unsigned short* lds) {
    const int t = threadIdx.x;  // blockDim == 256
    #pragma unroll
    for (int i = 0; i < 4; ++i) {
        int slot = i * 256 + t;          // 16B slot 0..1023 (8 per row)
        int row = slot >> 3;
        int cl = (slot & 7) ^ (row & 7); // logical chunk for this stored slot
        const unsigned short* g = src + (long)row * ld + k0 + cl * 8;
        __builtin_amdgcn_global_load_lds((const __attribute__((address_space(1))) void*)g,
                                         (__attribute__((address_space(3))) void*)(lds + (size_t)slot * 8),
                                         16, 0, 0);
    }
}

__device__ __forceinline__ bf16x8 read_frag(const unsigned short* lds, int r, int chunk) {
    int byte = (r << 7) + (((chunk ^ r) & 7) << 4) + ((chunk & ~7) << 4);
    return *(const bf16x8*)((const char*)lds + byte);
}

__device__ __forceinline__ void gemm_step(const unsigned short* As, const unsigned short* Bs,
                                          int arl, int brl, int lhi, f32x4 (&acc)[4][4]) {
    #pragma unroll
    for (int ks = 0; ks < 2; ++ks) {
        bf16x8 a[4], b[4];
        #pragma unroll
        for (int m = 0; m < 4; ++m) a[m] = read_frag(As, arl + m * 16, ks * 4 + lhi);
        #pragma unroll
        for (int n = 0; n < 4; ++n) b[n] = read_frag(Bs, brl + n * 16, ks * 4 + lhi);
        #pragma unroll
        for (int m = 0; m < 4; ++m)
            #pragma unroll
            for (int n = 0; n < 4; ++n)
                acc[m][n] = __builtin_amdgcn_mfma_f32_16x16x32_bf16(a[m], b[n], acc[m][n], 0, 0, 0);
    }
}

// ---------------- row-normalize FF -> bf16 FFnb ----------------
__global__ __launch_bounds__(128) void k_normalize(const float* __restrict__ FF,
                                                   unsigned short* __restrict__ FFnb) {
    int row = blockIdx.x;
    int tid = threadIdx.x;
    const float* src = FF + (size_t)row * CC;
    float v0 = src[tid], v1 = src[tid + 128], v2 = src[tid + 256];
    float s = v0 * v0 + v1 * v1 + v2 * v2;
    #pragma unroll
    for (int off = 32; off > 0; off >>= 1) s += __shfl_down(s, off, 64);
    __shared__ float ls[2];
    if ((tid & 63) == 0) ls[tid >> 6] = s;
    __syncthreads();
    float inv = 1.0f / sqrtf(ls[0] + ls[1]);
    unsigned short* dst = FFnb + (size_t)row * CC;
    dst[tid] = f2bf(v0 * inv);
    dst[tid + 128] = f2bf(v1 * inv);
    dst[tid + 256] = f2bf(v2 * inv);
}

// ---------------- kNN: one wave per (pixel-row, image, variant) task ----------------
__global__ __launch_bounds__(256) void k_knn(const float* __restrict__ im,
                                             unsigned char* __restrict__ res20,
                                             unsigned char* __restrict__ res10) {
    const int lane = threadIdx.x & 63;
    const int id = blockIdx.x * 4 + (threadIdx.x >> 6);   // 0..16383
    const int v = id & 1;
    const int rest = id >> 1;
    const int p = rest & 1023;
    const int b = rest >> 10;
    const float dw = v ? 0.1f : 2.0f;
    const int kneigh = v ? 10 : 20;
    const float* im0 = im + (size_t)b * 3 * HWP;
    const float scale = dw * (1.0f / 31.0f);
    float rf0 = (im0[p] + 1.f) * 0.5f;
    float rf1 = (im0[HWP + p] + 1.f) * 0.5f;
    float rf2 = (im0[2 * HWP + p] + 1.f) * 0.5f;
    float rx = (float)(p & 31) * scale;
    float ry = (float)(p >> 5) * scale;
    unsigned long long key[16];
    #pragma unroll
    for (int e = 0; e < 16; ++e) {
        int q = e * 64 + lane;
        float f0 = (im0[q] + 1.f) * 0.5f - rf0;
        float f1 = (im0[HWP + q] + 1.f) * 0.5f - rf1;
        float f2 = (im0[2 * HWP + q] + 1.f) * 0.5f - rf2;
        float fx = (float)(q & 31) * scale - rx;
        float fy = (float)(q >> 5) * scale - ry;
        float d = f0 * f0 + f1 * f1 + f2 * f2 + fx * fx + fy * fy;
        unsigned int db = __float_as_uint(d);
        key[e] = (q == p) ? ~0ull : ((((unsigned long long)db) << 10) | (unsigned int)q);
    }
    unsigned int selmask = 0;
    for (int it = 0; it < kneigh; ++it) {
        unsigned long long m = key[0];
        #pragma unroll
        for (int e = 1; e < 16; ++e) m = (key[e] < m) ? key[e] : m;
        #pragma unroll
        for (int off = 1; off < 64; off <<= 1) {
            unsigned long long o = __shfl_xor((unsigned long long)m, off, 64);
            m = (o < m) ? o : m;
        }
        int q = (int)(m & 1023u);
        if ((q & 63) == lane) {
            int e = q >> 6;
            selmask |= 1u << e;
            key[e] = ~0ull;
        }
    }
    unsigned char* dst = (v ? res10 : res20) + ((size_t)(b * HWP + p)) * HWP;
    #pragma unroll
    for (int e = 0; e < 16; ++e) dst[e * 64 + lane] = (unsigned char)((selmask >> e) & 1u);
}

// ---------------- A (symmetric): upper-triangle tiles only; mirror via LDS transpose ----------------
__global__ __launch_bounds__(256, 2) void k_gram(const unsigned short* __restrict__ FFnb,
                                                 const unsigned char* __restrict__ res20,
                                                 const unsigned char* __restrict__ res10,
                                                 unsigned short* __restrict__ A,
                                                 float* __restrict__ rowsum) {
    __shared__ __align__(16) unsigned short Sh[128 * 128];   // staging (2x128x64) then transpose buf
    unsigned short* As = Sh;
    unsigned short* Bs = Sh + 128 * 64;
    // bijective XCD swizzle over 2080 triangular tiles (2080 % 8 == 0)
    int s = ((blockIdx.x & 7) * 260) + (blockIdx.x >> 3);
    int ti = 0, rem = s;
    while (rem >= 64 - ti) { rem -= 64 - ti; ++ti; }   // row-major triangular decode, ti <= tj
    const int tj = ti + rem;
    const int row0 = ti * 128, col0 = tj * 128;
    const int tid = threadIdx.x, l = tid & 63, wid = tid >> 6;
    const int wr = (wid >> 1) * 64, wc = (wid & 1) * 64;
    const int arl = wr + (l & 15), brl = wc + (l & 15), lhi = l >> 4;
    f32x4 z = {0.f, 0.f, 0.f, 0.f};
    f32x4 acc[4][4];
    #pragma unroll
    for (int m = 0; m < 4; ++m)
        #pragma unroll
        for (int n = 0; n < 4; ++n) acc[m][n] = z;

    for (int k0 = 0; k0 < CC; k0 += 64) {
        stage_tile(FFnb + (long)row0 * CC, CC, k0, As);
        stage_tile(FFnb + (long)col0 * CC, CC, k0, Bs);
        __syncthreads();
        gemm_step(As, Bs, arl, brl, lhi, acc);
        __syncthreads();
    }
    const bool diagBlk = (ti == tj) || ((row0 >> 10) == (col0 >> 10));
    const bool offd = (ti != tj);
    const long mbase = ((long)(row0 >> 10)) << 20;
    float rs[4][4];
    float cs[4] = {0.f, 0.f, 0.f, 0.f};
    #pragma unroll
    for (int m = 0; m < 4; ++m)
        #pragma unroll
        for (int r = 0; r < 4; ++r) rs[m][r] = 0.f;
    #pragma unroll
    for (int m = 0; m < 4; ++m) {
        #pragma unroll
        for (int n = 0; n < 4; ++n) {
            #pragma unroll
            for (int r = 0; r < 4; ++r) {
                int gi = row0 + wr + m * 16 + lhi * 4 + r;
                int gj = col0 + wc + n * 16 + (l & 15);
                float vv = acc[m][n][r];
                vv = (gi == gj) ? 0.f : fmaxf(vv, 0.f);
                if (diagBlk) {
                    int li = gi & 1023, lj = gj & 1023;
                    unsigned char mm = (unsigned char)(
                        (res20[mbase + (long)li * HWP + lj] & res20[mbase + (long)lj * HWP + li]) |
                        (res10[mbase + (long)li * HWP + lj] & res10[mbase + (long)lj * HWP + li]));
                    vv += 0.1f * (float)mm;
                }
                unsigned short u = f2bf(vv);
                A[(long)gi * NN + gj] = u;
                rs[m][r] += vv;
                if (offd) {
                    cs[n] += vv;
                    int jl = wc + n * 16 + (l & 15);
                    int il = wr + m * 16 + lhi * 4 + r;
                    *(unsigned short*)((char*)Sh + jl * 256 + ((il * 2) ^ ((jl & 15) << 4))) = u;
                }
            }
        }
    }
    // row partials: reduce over the 16 lanes (l&15) sharing (lhi, m, r)
    #pragma unroll
    for (int m = 0; m < 4; ++m)
        #pragma unroll
        for (int r = 0; r < 4; ++r) {
            float p = rs[m][r];
            #pragma unroll
            for (int off = 1; off < 16; off <<= 1) p += __shfl_xor(p, off, 64);
            if ((l & 15) == 0) atomicAdd(&rowsum[row0 + wr + m * 16 + lhi * 4 + r], p);
        }
    if (offd) {
        // col partials: reduce over lhi (lanes l^16, l^32), add to rowsum[col]
        #pragma unroll
        for (int n = 0; n < 4; ++n) {
            float p = cs[n];
            p += __shfl_xor(p, 16, 64);
            p += __shfl_xor(p, 32, 64);
            if (l < 16) atomicAdd(&rowsum[col0 + wc + n * 16 + l], p);
        }
        // mirror tile: coalesced read of transposed LDS buffer -> A[col][row]
        __syncthreads();
        #pragma unroll
        for (int p8 = 0; p8 < 8; ++p8) {
            int idx = p8 * 2048 + tid * 8;
            int jj = idx >> 7;
            int i0 = idx & 127;
            bf16x8 vvv = *(const bf16x8*)((const char*)Sh + jj * 256 + ((i0 * 2) ^ ((jj & 15) << 4)));
            *(bf16x8*)(A + (long)(col0 + jj) * NN + row0 + i0) = vvv;
        }
    }
}

// ---------------- D = rsqrt(rowsum/(N-1)) ----------------
__global__ __launch_bounds__(256) void k_d(const float* __restrict__ rowsum,
                                           float* __restrict__ Dv) {
    int i = blockIdx.x * 256 + threadIdx.x;
    Dv[i] = 1.0f / sqrtf(rowsum[i] * (1.0f / 8191.0f));
}

// ---------------- Psi transposes via LDS tile: PaT=(T/N)Psi^T, PsT=PaT*Dv (bf16) ----------------
__global__ __launch_bounds__(256) void k_psiT(const float* __restrict__ Psi,
                                              const float* __restrict__ Dv,
                                              unsigned short* __restrict__ PaT,
                                              unsigned short* __restrict__ PsT) {
    __shared__ unsigned short tile[128][72];
    __shared__ float Dvs[64];
    const int j0 = blockIdx.x * 64;    // 128 blocks
    const int n0 = blockIdx.y * 128;   // 4 blocks
    const int t = threadIdx.x;
    if (t < 64) Dvs[t] = Dv[j0 + t];
    #pragma unroll
    for (int i = 0; i < 8; ++i) {
        int jl = i * 8 + (t >> 5);
        int c4 = (t & 31) * 4;
        float4 vv = *(const float4*)(Psi + (size_t)(j0 + jl) * KD + n0 + c4);
        tile[c4 + 0][jl] = f2bf(vv.x * T_OVER_N);
        tile[c4 + 1][jl] = f2bf(vv.y * T_OVER_N);
        tile[c4 + 2][jl] = f2bf(vv.z * T_OVER_N);
        tile[c4 + 3][jl] = f2bf(vv.w * T_OVER_N);
    }
    __syncthreads();
    const int nl = t >> 1;
    const int jh = (t & 1) * 32;
    unsigned short pa[32], ps[32];
    #pragma unroll
    for (int jj = 0; jj < 32; ++jj) {
        unsigned short u = tile[nl][jh + jj];
        pa[jj] = u;
        ps[jj] = f2bf(bf2f(u) * Dvs[jh + jj]);
    }
    unsigned short* dpa = PaT + (size_t)(n0 + nl) * NN + j0 + jh;
    unsigned short* dps = PsT + (size_t)(n0 + nl) * NN + j0 + jh;
    #pragma unroll
    for (int c = 0; c < 4; ++c) {
        *(bf16x8*)(dpa + c * 8) = *(const bf16x8*)(pa + c * 8);
        *(bf16x8*)(dps + c * 8) = *(const bf16x8*)(ps + c * 8);
    }
}

// ---------------- YTacc[n][i] += sum_{k-chunk} PsT[n][k] * A[i][k]  (K-split x4, XCD-local atomics) ----------------
// All 16 blocks (4 nt x 4 kz) of a given it-tile land on XCD (it & 7): atomics stay in one L2,
// and the A row-panel is fetched once per XCD.
__global__ __launch_bounds__(256, 4) void k_ytks(const unsigned short* __restrict__ PsT,
                                                 const unsigned short* __restrict__ A,
                                                 float* __restrict__ YTacc) {
    __shared__ __align__(16) unsigned short As[128 * 64];
    __shared__ __align__(16) unsigned short Bs[128 * 64];
    const int b = blockIdx.x;            // 1024 blocks
    const int xcd = b & 7;
    const int rest = b >> 3;             // 0..127
    const int it = xcd + (rest & 7) * 8; // it ≡ b (mod 8)
    const int sub = rest >> 3;           // 0..15
    const int nt = sub & 3, kz = sub >> 2;
    const int row0 = nt * 128, col0 = it * 128;
    const int tid = threadIdx.x, l = tid & 63, wid = tid >> 6;
    const int wr = (wid >> 1) * 64, wc = (wid & 1) * 64;
    const int arl = wr + (l & 15), brl = wc + (l & 15), lhi = l >> 4;
    f32x4 z = {0.f, 0.f, 0.f, 0.f};
    f32x4 acc[4][4];
    #pragma unroll
    for (int m = 0; m < 4; ++m)
        #pragma unroll
        for (int n = 0; n < 4; ++n) acc[m][n] = z;

    const int kbeg = kz * 2048;
    for (int k0 = kbeg; k0 < kbeg + 2048; k0 += 64) {
        stage_tile(PsT + (long)row0 * NN, NN, k0, As);
        stage_tile(A + (long)col0 * NN, NN, k0, Bs);
        __syncthreads();
        gemm_step(As, Bs, arl, brl, lhi, acc);
        __syncthreads();
    }
    #pragma unroll
    for (int m = 0; m < 4; ++m) {
        #pragma unroll
        for (int n = 0; n < 4; ++n) {
            #pragma unroll
            for (int r = 0; r < 4; ++r) {
                int gi = row0 + wr + m * 16 + lhi * 4 + r;
                int gj = col0 + wc + n * 16 + (l & 15);
                atomicAdd(&YTacc[(long)gi * NN + gj], acc[m][n][r]);
            }
        }
    }
}

// ---------------- YT = bf16(YTacc * Dv[col]) ----------------
__global__ __launch_bounds__(256) void k_ytfin(const float* __restrict__ YTacc,
                                               const float* __restrict__ Dv,
                                               unsigned short* __restrict__ YT) {
    long idx8 = ((long)blockIdx.x * 256 + threadIdx.x) * 8;
    int i = (int)(idx8 & (NN - 1));
    float4 a0 = *(const float4*)(YTacc + idx8);
    float4 a1 = *(const float4*)(YTacc + idx8 + 4);
    float4 d0 = *(const float4*)(Dv + i);
    float4 d1 = *(const float4*)(Dv + i + 4);
    bf16x8 o;
    o[0] = (short)f2bf(a0.x * d0.x); o[1] = (short)f2bf(a0.y * d0.y);
    o[2] = (short)f2bf(a0.z * d0.z); o[3] = (short)f2bf(a0.w * d0.w);
    o[4] = (short)f2bf(a1.x * d1.x); o[5] = (short)f2bf(a1.y * d1.y);
    o[6] = (short)f2bf(a1.z * d1.z); o[7] = (short)f2bf(a1.w * d1.w);
    *(bf16x8*)(YT + idx8) = o;
}

// ---------------- R += PaT-tile * YT-tile^T (dense triangular grid, K-split x8 of 1024) ----------------
__global__ __launch_bounds__(256, 2) void k_r(const unsigned short* __restrict__ PaT,
                                              const unsigned short* __restrict__ YT,
                                              float* __restrict__ R) {
    static const int t1tab[10] = {0,0,0,0,1,1,1,2,2,3};
    static const int t2tab[10] = {0,1,2,3,1,2,3,2,3,3};
    const int t1 = t1tab[blockIdx.x], t2 = t2tab[blockIdx.x], kz = blockIdx.y;
    __shared__ __align__(16) unsigned short As[128 * 64];
    __shared__ __align__(16) unsigned short Bs[128 * 64];
    const int row0 = t1 * 128, col0 = t2 * 128;
    const int tid = threadIdx.x, l = tid & 63, wid = tid >> 6;
    const int wr = (wid >> 1) * 64, wc = (wid & 1) * 64;
    const int arl = wr + (l & 15), brl = wc + (l & 15), lhi = l >> 4;
    f32x4 z = {0.f, 0.f, 0.f, 0.f};
    f32x4 acc[4][4];
    #pragma unroll
    for (int m = 0; m < 4; ++m)
        #pragma unroll
        for (int n = 0; n < 4; ++n) acc[m][n] = z;

    const int kbeg = kz * 1024;
    for (int k0 = kbeg; k0 < kbeg + 1024; k0 += 64) {
        stage_tile(PaT + (long)row0 * NN, NN, k0, As);
        stage_tile(YT + (long)col0 * NN, NN, k0, Bs);
        __syncthreads();
        gemm_step(As, Bs, arl, brl, lhi, acc);
        __syncthreads();
    }
    #pragma unroll
    for (int m = 0; m < 4; ++m) {
        #pragma unroll
        for (int n = 0; n < 4; ++n) {
            #pragma unroll
            for (int r = 0; r < 4; ++r) {
                int gk1 = row0 + wr + m * 16 + lhi * 4 + r;
                int gk2 = col0 + wc + n * 16 + (l & 15);
                atomicAdd(&R[(long)gk1 * KD + gk2], acc[m][n][r]);
            }
        }
    }
}

// ---------------- trace & triu^2 reduction of R ----------------
__global__ __launch_bounds__(256) void k_tri(const float* __restrict__ R,
                                             float* __restrict__ acc2) {
    float tr = 0.f, rg = 0.f;
    for (int idx = blockIdx.x * 256 + threadIdx.x; idx < KD * KD; idx += 64 * 256) {
        int k1 = idx >> 9, k2 = idx & 511;
        float v = R[idx];
        if (k1 == k2) tr += v;
        else if (k1 < k2) rg += v * v;
    }
    #pragma unroll
    for (int off = 32; off > 0; off >>= 1) {
        tr += __shfl_down(tr, off, 64);
        rg += __shfl_down(rg, off, 64);
    }
    __shared__ float lt[4], lr[4];
    int tid = threadIdx.x;
    if ((tid & 63) == 0) { lt[tid >> 6] = tr; lr[tid >> 6] = rg; }
    __syncthreads();
    if (tid == 0) {
        atomicAdd(&acc2[0], lt[0] + lt[1] + lt[2] + lt[3]);
        atomicAdd(&acc2[1], lr[0] + lr[1] + lr[2] + lr[3]);
    }
}

// ---------------- finalize ----------------
__global__ void k_fin(const float* __restrict__ acc2, float* __restrict__ out) {
    out[0] = -acc2[0];
    out[1] = 0.05f * acc2[1];
}

extern "C" void kernel_launch(void* const* d_in, const int* in_sizes, int n_in,
                              void* d_out, int out_size, void* d_ws, size_t ws_size,
                              hipStream_t stream) {
    const float* FF  = (const float*)d_in[0];
    const float* Psi = (const float*)d_in[1];
    const float* im  = (const float*)d_in[2];
    float* out = (float*)d_out;
    char* ws = (char*)d_ws;
    size_t off = 0;
    auto alloc = [&](size_t bytes) {
        size_t o = off;
        off += (bytes + 255) & ~(size_t)255;
        return o;
    };
    unsigned short* FFnb  = (unsigned short*)(ws + alloc((size_t)NN * CC * 2));
    unsigned char* res20  = (unsigned char*)(ws + alloc((size_t)8 * HWP * HWP));
    unsigned char* res10  = (unsigned char*)(ws + alloc((size_t)8 * HWP * HWP));
    float* rowsum         = (float*)(ws + alloc((size_t)NN * 4));
    float* Dv             = (float*)(ws + alloc((size_t)NN * 4));
    unsigned short* PaT   = (unsigned short*)(ws + alloc((size_t)KD * NN * 2));
    unsigned short* PsT   = (unsigned short*)(ws + alloc((size_t)KD * NN * 2));
    unsigned short* YT    = (unsigned short*)(ws + alloc((size_t)KD * NN * 2));
    float* YTacc          = (float*)(ws + alloc((size_t)KD * NN * 4));
    float* R              = (float*)(ws + alloc((size_t)KD * KD * 4));
    float* acc2           = (float*)(ws + alloc(256));
    unsigned short* A     = (unsigned short*)(ws + alloc((size_t)NN * NN * 2));

    hipMemsetAsync(rowsum, 0, (size_t)NN * 4, stream);
    hipMemsetAsync(YTacc, 0, (size_t)KD * NN * 4, stream);
    hipMemsetAsync(R, 0, (size_t)KD * KD * 4, stream);
    hipMemsetAsync(acc2, 0, 8, stream);

    k_normalize<<<NN, 128, 0, stream>>>(FF, FFnb);
    k_knn<<<4096, 256, 0, stream>>>(im, res20, res10);
    k_gram<<<2080, 256, 0, stream>>>(FFnb, res20, res10, A, rowsum);
    k_d<<<NN / 256, 256, 0, stream>>>(rowsum, Dv);
    k_psiT<<<dim3(128, 4), 256, 0, stream>>>(Psi, Dv, PaT, PsT);
    k_ytks<<<1024, 256, 0, stream>>>(PsT, A, YTacc);
    k_ytfin<<<(KD * NN) / (256 * 8), 256, 0, stream>>>(YTacc, Dv, YT);
    k_r<<<dim3(10, 8), 256, 0, stream>>>(PaT, YT, R);
    k_tri<<<64, 256, 0, stream>>>(R, acc2);
    k_fin<<<1, 1, 0, stream>>>(acc2, out);
}

// Round 8
// 347.929 us; speedup vs baseline: 6.0306x; 1.0112x over previous
//
#include <hip/hip_runtime.h>
#include <hip/hip_bf16.h>

#define NN 8192
#define CC 384
#define KD 512
#define HWP 1024

typedef __attribute__((ext_vector_type(8))) short bf16x8;
typedef __attribute__((ext_vector_type(4))) float f32x4;

static constexpr float T_OVER_N = 10.0f / 8192.0f;

__device__ __forceinline__ float bf2f(unsigned short u) {
    union { unsigned int i; float f; } x;
    x.i = ((unsigned int)u) << 16;
    return x.f;
}
__device__ __forceinline__ unsigned short f2bf(float f) {
    __hip_bfloat16 h = __float2bfloat16(f);
    unsigned short u;
    __builtin_memcpy(&u, &h, sizeof(u));
    return u;
}

// ---- pipeline fences (T3 minimum 2-phase): counted vmcnt, raw barrier, sched fences ----
__device__ __forceinline__ void wait_vm8() {
    asm volatile("s_waitcnt vmcnt(8)" ::: "memory");
    __builtin_amdgcn_sched_barrier(0);
}
__device__ __forceinline__ void wait_vm0() {
    asm volatile("s_waitcnt vmcnt(0)" ::: "memory");
    __builtin_amdgcn_sched_barrier(0);
}
__device__ __forceinline__ void rawbar() {
    __builtin_amdgcn_s_barrier();
    __builtin_amdgcn_sched_barrier(0);
}

// ---------- 128x64 bf16 tile staging via global_load_lds (16B), source-side XOR swizzle ----------
__device__ __forceinline__ void stage_tile(const unsigned short* __restrict__ src, long ld,
                                           int k0, unsigned short* lds) {
    const int t = threadIdx.x;  // blockDim == 256
    #pragma unroll
    for (int i = 0; i < 4; ++i) {
        int slot = i * 256 + t;          // 16B slot 0..1023 (8 per row)
        int row = slot >> 3;
        int cl = (slot & 7) ^ (row & 7); // logical chunk for this stored slot
        const unsigned short* g = src + (long)row * ld + k0 + cl * 8;
        __builtin_amdgcn_global_load_lds((const __attribute__((address_space(1))) void*)g,
                                         (__attribute__((address_space(3))) void*)(lds + (size_t)slot * 8),
                                         16, 0, 0);
    }
}

__device__ __forceinline__ bf16x8 read_frag(const unsigned short* lds, int r, int chunk) {
    int byte = (r << 7) + (((chunk ^ r) & 7) << 4) + ((chunk & ~7) << 4);
    return *(const bf16x8*)((const char*)lds + byte);
}

__device__ __forceinline__ void gemm_step(const unsigned short* As, const unsigned short* Bs,
                                          int arl, int brl, int lhi, f32x4 (&acc)[4][4]) {
    #pragma unroll
    for (int ks = 0; ks < 2; ++ks) {
        bf16x8 a[4], b[4];
        #pragma unroll
        for (int m = 0; m < 4; ++m) a[m] = read_frag(As, arl + m * 16, ks * 4 + lhi);
        #pragma unroll
        for (int n = 0; n < 4; ++n) b[n] = read_frag(Bs, brl + n * 16, ks * 4 + lhi);
        #pragma unroll
        for (int m = 0; m < 4; ++m)
            #pragma unroll
            for (int n = 0; n < 4; ++n)
                acc[m][n] = __builtin_amdgcn_mfma_f32_16x16x32_bf16(a[m], b[n], acc[m][n], 0, 0, 0);
    }
}

// ---------------- row-normalize FF -> bf16 FFnb ----------------
__global__ __launch_bounds__(128) void k_normalize(const float* __restrict__ FF,
                                                   unsigned short* __restrict__ FFnb) {
    int row = blockIdx.x;
    int tid = threadIdx.x;
    const float* src = FF + (size_t)row * CC;
    float v0 = src[tid], v1 = src[tid + 128], v2 = src[tid + 256];
    float s = v0 * v0 + v1 * v1 + v2 * v2;
    #pragma unroll
    for (int off = 32; off > 0; off >>= 1) s += __shfl_down(s, off, 64);
    __shared__ float ls[2];
    if ((tid & 63) == 0) ls[tid >> 6] = s;
    __syncthreads();
    float inv = 1.0f / sqrtf(ls[0] + ls[1]);
    unsigned short* dst = FFnb + (size_t)row * CC;
    dst[tid] = f2bf(v0 * inv);
    dst[tid + 128] = f2bf(v1 * inv);
    dst[tid + 256] = f2bf(v2 * inv);
}

// ---------------- kNN: one wave per (pixel-row, image, variant) task ----------------
__global__ __launch_bounds__(256) void k_knn(const float* __restrict__ im,
                                             unsigned char* __restrict__ res20,
                                             unsigned char* __restrict__ res10) {
    const int lane = threadIdx.x & 63;
    const int id = blockIdx.x * 4 + (threadIdx.x >> 6);   // 0..16383
    const int v = id & 1;
    const int rest = id >> 1;
    const int p = rest & 1023;
    const int b = rest >> 10;
    const float dw = v ? 0.1f : 2.0f;
    const int kneigh = v ? 10 : 20;
    const float* im0 = im + (size_t)b * 3 * HWP;
    const float scale = dw * (1.0f / 31.0f);
    float rf0 = (im0[p] + 1.f) * 0.5f;
    float rf1 = (im0[HWP + p] + 1.f) * 0.5f;
    float rf2 = (im0[2 * HWP + p] + 1.f) * 0.5f;
    float rx = (float)(p & 31) * scale;
    float ry = (float)(p >> 5) * scale;
    unsigned long long key[16];
    #pragma unroll
    for (int e = 0; e < 16; ++e) {
        int q = e * 64 + lane;
        float f0 = (im0[q] + 1.f) * 0.5f - rf0;
        float f1 = (im0[HWP + q] + 1.f) * 0.5f - rf1;
        float f2 = (im0[2 * HWP + q] + 1.f) * 0.5f - rf2;
        float fx = (float)(q & 31) * scale - rx;
        float fy = (float)(q >> 5) * scale - ry;
        float d = f0 * f0 + f1 * f1 + f2 * f2 + fx * fx + fy * fy;
        unsigned int db = __float_as_uint(d);
        key[e] = (q == p) ? ~0ull : ((((unsigned long long)db) << 10) | (unsigned int)q);
    }
    unsigned int selmask = 0;
    for (int it = 0; it < kneigh; ++it) {
        unsigned long long m = key[0];
        #pragma unroll
        for (int e = 1; e < 16; ++e) m = (key[e] < m) ? key[e] : m;
        #pragma unroll
        for (int off = 1; off < 64; off <<= 1) {
            unsigned long long o = __shfl_xor((unsigned long long)m, off, 64);
            m = (o < m) ? o : m;
        }
        int q = (int)(m & 1023u);
        if ((q & 63) == lane) {
            int e = q >> 6;
            selmask |= 1u << e;
            key[e] = ~0ull;
        }
    }
    unsigned char* dst = (v ? res10 : res20) + ((size_t)(b * HWP + p)) * HWP;
    #pragma unroll
    for (int e = 0; e < 16; ++e) dst[e * 64 + lane] = (unsigned char)((selmask >> e) & 1u);
}

// ---------------- A (symmetric): upper-triangle tiles only; 2-phase pipelined K-loop ----------------
__global__ __launch_bounds__(256, 2) void k_gram(const unsigned short* __restrict__ FFnb,
                                                 const unsigned char* __restrict__ res20,
                                                 const unsigned char* __restrict__ res10,
                                                 unsigned short* __restrict__ A,
                                                 float* __restrict__ rowsum) {
    __shared__ __align__(16) unsigned short Sh[4][8192];   // dbuf: A0,B0,A1,B1 (16KB each)
    // bijective XCD swizzle over 2080 triangular tiles (2080 % 8 == 0)
    int s = ((blockIdx.x & 7) * 260) + (blockIdx.x >> 3);
    int ti = 0, rem = s;
    while (rem >= 64 - ti) { rem -= 64 - ti; ++ti; }   // row-major triangular decode, ti <= tj
    const int tj = ti + rem;
    const int row0 = ti * 128, col0 = tj * 128;
    const int tid = threadIdx.x, l = tid & 63, wid = tid >> 6;
    const int wr = (wid >> 1) * 64, wc = (wid & 1) * 64;
    const int arl = wr + (l & 15), brl = wc + (l & 15), lhi = l >> 4;
    f32x4 z = {0.f, 0.f, 0.f, 0.f};
    f32x4 acc[4][4];
    #pragma unroll
    for (int m = 0; m < 4; ++m)
        #pragma unroll
        for (int n = 0; n < 4; ++n) acc[m][n] = z;

    stage_tile(FFnb + (long)row0 * CC, CC, 0, Sh[0]);
    stage_tile(FFnb + (long)col0 * CC, CC, 0, Sh[1]);
    for (int t = 0; t < 6; ++t) {
        const int cur = t & 1, nxt = cur ^ 1;
        if (t + 1 < 6) {
            stage_tile(FFnb + (long)row0 * CC, CC, (t + 1) * 64, Sh[2 * nxt]);
            stage_tile(FFnb + (long)col0 * CC, CC, (t + 1) * 64, Sh[2 * nxt + 1]);
            wait_vm8();
        } else {
            wait_vm0();
        }
        rawbar();
        gemm_step(Sh[2 * cur], Sh[2 * cur + 1], arl, brl, lhi, acc);
        rawbar();
    }
    const bool diagBlk = (ti == tj) || ((row0 >> 10) == (col0 >> 10));
    const bool offd = (ti != tj);
    const long mbase = ((long)(row0 >> 10)) << 20;
    float rs[4][4];
    float cs[4] = {0.f, 0.f, 0.f, 0.f};
    #pragma unroll
    for (int m = 0; m < 4; ++m)
        #pragma unroll
        for (int r = 0; r < 4; ++r) rs[m][r] = 0.f;
    #pragma unroll
    for (int m = 0; m < 4; ++m) {
        #pragma unroll
        for (int n = 0; n < 4; ++n) {
            #pragma unroll
            for (int r = 0; r < 4; ++r) {
                int gi = row0 + wr + m * 16 + lhi * 4 + r;
                int gj = col0 + wc + n * 16 + (l & 15);
                float vv = acc[m][n][r];
                vv = (gi == gj) ? 0.f : fmaxf(vv, 0.f);
                if (diagBlk) {
                    int li = gi & 1023, lj = gj & 1023;
                    unsigned char mm = (unsigned char)(
                        (res20[mbase + (long)li * HWP + lj] & res20[mbase + (long)lj * HWP + li]) |
                        (res10[mbase + (long)li * HWP + lj] & res10[mbase + (long)lj * HWP + li]));
                    vv += 0.1f * (float)mm;
                }
                unsigned short u = f2bf(vv);
                A[(long)gi * NN + gj] = u;
                rs[m][r] += vv;
                if (offd) {
                    cs[n] += vv;
                    // transpose scatter into Sh[0..1] region (last compute used Sh[2..3])
                    int jl = wc + n * 16 + (l & 15);
                    int il = wr + m * 16 + lhi * 4 + r;
                    *(unsigned short*)((char*)Sh + jl * 256 + ((il * 2) ^ ((jl & 15) << 4))) = u;
                }
            }
        }
    }
    // row partials: reduce over the 16 lanes (l&15) sharing (lhi, m, r)
    #pragma unroll
    for (int m = 0; m < 4; ++m)
        #pragma unroll
        for (int r = 0; r < 4; ++r) {
            float p = rs[m][r];
            #pragma unroll
            for (int off = 1; off < 16; off <<= 1) p += __shfl_xor(p, off, 64);
            if ((l & 15) == 0) atomicAdd(&rowsum[row0 + wr + m * 16 + lhi * 4 + r], p);
        }
    if (offd) {
        // col partials: reduce over lhi (lanes l^16, l^32), add to rowsum[col]
        #pragma unroll
        for (int n = 0; n < 4; ++n) {
            float p = cs[n];
            p += __shfl_xor(p, 16, 64);
            p += __shfl_xor(p, 32, 64);
            if (l < 16) atomicAdd(&rowsum[col0 + wc + n * 16 + l], p);
        }
        // mirror tile: coalesced read of transposed LDS buffer -> A[col][row]
        __syncthreads();
        #pragma unroll
        for (int p8 = 0; p8 < 8; ++p8) {
            int idx = p8 * 2048 + tid * 8;
            int jj = idx >> 7;
            int i0 = idx & 127;
            bf16x8 vvv = *(const bf16x8*)((const char*)Sh + jj * 256 + ((i0 * 2) ^ ((jj & 15) << 4)));
            *(bf16x8*)(A + (long)(col0 + jj) * NN + row0 + i0) = vvv;
        }
    }
}

// ---------------- D = rsqrt(rowsum/(N-1)) ----------------
__global__ __launch_bounds__(256) void k_d(const float* __restrict__ rowsum,
                                           float* __restrict__ Dv) {
    int i = blockIdx.x * 256 + threadIdx.x;
    Dv[i] = 1.0f / sqrtf(rowsum[i] * (1.0f / 8191.0f));
}

// ---------------- Psi transposes via LDS tile: PaT=(T/N)Psi^T, PsT=PaT*Dv (bf16) ----------------
__global__ __launch_bounds__(256) void k_psiT(const float* __restrict__ Psi,
                                              const float* __restrict__ Dv,
                                              unsigned short* __restrict__ PaT,
                                              unsigned short* __restrict__ PsT) {
    __shared__ unsigned short tile[128][72];
    __shared__ float Dvs[64];
    const int j0 = blockIdx.x * 64;    // 128 blocks
    const int n0 = blockIdx.y * 128;   // 4 blocks
    const int t = threadIdx.x;
    if (t < 64) Dvs[t] = Dv[j0 + t];
    #pragma unroll
    for (int i = 0; i < 8; ++i) {
        int jl = i * 8 + (t >> 5);
        int c4 = (t & 31) * 4;
        float4 vv = *(const float4*)(Psi + (size_t)(j0 + jl) * KD + n0 + c4);
        tile[c4 + 0][jl] = f2bf(vv.x * T_OVER_N);
        tile[c4 + 1][jl] = f2bf(vv.y * T_OVER_N);
        tile[c4 + 2][jl] = f2bf(vv.z * T_OVER_N);
        tile[c4 + 3][jl] = f2bf(vv.w * T_OVER_N);
    }
    __syncthreads();
    const int nl = t >> 1;
    const int jh = (t & 1) * 32;
    unsigned short pa[32], ps[32];
    #pragma unroll
    for (int jj = 0; jj < 32; ++jj) {
        unsigned short u = tile[nl][jh + jj];
        pa[jj] = u;
        ps[jj] = f2bf(bf2f(u) * Dvs[jh + jj]);
    }
    unsigned short* dpa = PaT + (size_t)(n0 + nl) * NN + j0 + jh;
    unsigned short* dps = PsT + (size_t)(n0 + nl) * NN + j0 + jh;
    #pragma unroll
    for (int c = 0; c < 4; ++c) {
        *(bf16x8*)(dpa + c * 8) = *(const bf16x8*)(pa + c * 8);
        *(bf16x8*)(dps + c * 8) = *(const bf16x8*)(ps + c * 8);
    }
}

// ---------------- YTacc[n][i] += PsT[n][k-chunk] * A[i][k-chunk]  (2-phase pipelined) ----------------
__global__ __launch_bounds__(256, 2) void k_ytks(const unsigned short* __restrict__ PsT,
                                                 const unsigned short* __restrict__ A,
                                                 float* __restrict__ YTacc) {
    __shared__ __align__(16) unsigned short Sh[4][8192];
    const int b = blockIdx.x;            // 1024 blocks
    const int xcd = b & 7;
    const int rest = b >> 3;             // 0..127
    const int it = xcd + (rest & 7) * 8; // it ≡ b (mod 8): XCD-local atomics + A panel reuse
    const int sub = rest >> 3;           // 0..15
    const int nt = sub & 3, kz = sub >> 2;
    const int row0 = nt * 128, col0 = it * 128;
    const int tid = threadIdx.x, l = tid & 63, wid = tid >> 6;
    const int wr = (wid >> 1) * 64, wc = (wid & 1) * 64;
    const int arl = wr + (l & 15), brl = wc + (l & 15), lhi = l >> 4;
    f32x4 z = {0.f, 0.f, 0.f, 0.f};
    f32x4 acc[4][4];
    #pragma unroll
    for (int m = 0; m < 4; ++m)
        #pragma unroll
        for (int n = 0; n < 4; ++n) acc[m][n] = z;

    const int kbeg = kz * 2048;
    stage_tile(PsT + (long)row0 * NN, NN, kbeg, Sh[0]);
    stage_tile(A + (long)col0 * NN, NN, kbeg, Sh[1]);
    for (int t = 0; t < 32; ++t) {
        const int cur = t & 1, nxt = cur ^ 1;
        if (t + 1 < 32) {
            int k1 = kbeg + (t + 1) * 64;
            stage_tile(PsT + (long)row0 * NN, NN, k1, Sh[2 * nxt]);
            stage_tile(A + (long)col0 * NN, NN, k1, Sh[2 * nxt + 1]);
            wait_vm8();
        } else {
            wait_vm0();
        }
        rawbar();
        gemm_step(Sh[2 * cur], Sh[2 * cur + 1], arl, brl, lhi, acc);
        rawbar();
    }
    #pragma unroll
    for (int m = 0; m < 4; ++m) {
        #pragma unroll
        for (int n = 0; n < 4; ++n) {
            #pragma unroll
            for (int r = 0; r < 4; ++r) {
                int gi = row0 + wr + m * 16 + lhi * 4 + r;
                int gj = col0 + wc + n * 16 + (l & 15);
                atomicAdd(&YTacc[(long)gi * NN + gj], acc[m][n][r]);
            }
        }
    }
}

// ---------------- YT = bf16(YTacc * Dv[col]) ----------------
__global__ __launch_bounds__(256) void k_ytfin(const float* __restrict__ YTacc,
                                               const float* __restrict__ Dv,
                                               unsigned short* __restrict__ YT) {
    long idx8 = ((long)blockIdx.x * 256 + threadIdx.x) * 8;
    int i = (int)(idx8 & (NN - 1));
    float4 a0 = *(const float4*)(YTacc + idx8);
    float4 a1 = *(const float4*)(YTacc + idx8 + 4);
    float4 d0 = *(const float4*)(Dv + i);
    float4 d1 = *(const float4*)(Dv + i + 4);
    bf16x8 o;
    o[0] = (short)f2bf(a0.x * d0.x); o[1] = (short)f2bf(a0.y * d0.y);
    o[2] = (short)f2bf(a0.z * d0.z); o[3] = (short)f2bf(a0.w * d0.w);
    o[4] = (short)f2bf(a1.x * d1.x); o[5] = (short)f2bf(a1.y * d1.y);
    o[6] = (short)f2bf(a1.z * d1.z); o[7] = (short)f2bf(a1.w * d1.w);
    *(bf16x8*)(YT + idx8) = o;
}

// ---------------- R += PaT-tile * YT-tile^T (2-phase pipelined, K-split x8) ----------------
__global__ __launch_bounds__(256, 2) void k_r(const unsigned short* __restrict__ PaT,
                                              const unsigned short* __restrict__ YT,
                                              float* __restrict__ R) {
    static const int t1tab[10] = {0,0,0,0,1,1,1,2,2,3};
    static const int t2tab[10] = {0,1,2,3,1,2,3,2,3,3};
    const int t1 = t1tab[blockIdx.x], t2 = t2tab[blockIdx.x], kz = blockIdx.y;
    __shared__ __align__(16) unsigned short Sh[4][8192];
    const int row0 = t1 * 128, col0 = t2 * 128;
    const int tid = threadIdx.x, l = tid & 63, wid = tid >> 6;
    const int wr = (wid >> 1) * 64, wc = (wid & 1) * 64;
    const int arl = wr + (l & 15), brl = wc + (l & 15), lhi = l >> 4;
    f32x4 z = {0.f, 0.f, 0.f, 0.f};
    f32x4 acc[4][4];
    #pragma unroll
    for (int m = 0; m < 4; ++m)
        #pragma unroll
        for (int n = 0; n < 4; ++n) acc[m][n] = z;

    const int kbeg = kz * 1024;
    stage_tile(PaT + (long)row0 * NN, NN, kbeg, Sh[0]);
    stage_tile(YT + (long)col0 * NN, NN, kbeg, Sh[1]);
    for (int t = 0; t < 16; ++t) {
        const int cur = t & 1, nxt = cur ^ 1;
        if (t + 1 < 16) {
            int k1 = kbeg + (t + 1) * 64;
            stage_tile(PaT + (long)row0 * NN, NN, k1, Sh[2 * nxt]);
            stage_tile(YT + (long)col0 * NN, NN, k1, Sh[2 * nxt + 1]);
            wait_vm8();
        } else {
            wait_vm0();
        }
        rawbar();
        gemm_step(Sh[2 * cur], Sh[2 * cur + 1], arl, brl, lhi, acc);
        rawbar();
    }
    #pragma unroll
    for (int m = 0; m < 4; ++m) {
        #pragma unroll
        for (int n = 0; n < 4; ++n) {
            #pragma unroll
            for (int r = 0; r < 4; ++r) {
                int gk1 = row0 + wr + m * 16 + lhi * 4 + r;
                int gk2 = col0 + wc + n * 16 + (l & 15);
                atomicAdd(&R[(long)gk1 * KD + gk2], acc[m][n][r]);
            }
        }
    }
}

// ---------------- trace & triu^2 reduction of R ----------------
__global__ __launch_bounds__(256) void k_tri(const float* __restrict__ R,
                                             float* __restrict__ acc2) {
    float tr = 0.f, rg = 0.f;
    for (int idx = blockIdx.x * 256 + threadIdx.x; idx < KD * KD; idx += 64 * 256) {
        int k1 = idx >> 9, k2 = idx & 511;
        float v = R[idx];
        if (k1 == k2) tr += v;
        else if (k1 < k2) rg += v * v;
    }
    #pragma unroll
    for (int off = 32; off > 0; off >>= 1) {
        tr += __shfl_down(tr, off, 64);
        rg += __shfl_down(rg, off, 64);
    }
    __shared__ float lt[4], lr[4];
    int tid = threadIdx.x;
    if ((tid & 63) == 0) { lt[tid >> 6] = tr; lr[tid >> 6] = rg; }
    __syncthreads();
    if (tid == 0) {
        atomicAdd(&acc2[0], lt[0] + lt[1] + lt[2] + lt[3]);
        atomicAdd(&acc2[1], lr[0] + lr[1] + lr[2] + lr[3]);
    }
}

// ---------------- finalize ----------------
__global__ void k_fin(const float* __restrict__ acc2, float* __restrict__ out) {
    out[0] = -acc2[0];
    out[1] = 0.05f * acc2[1];
}

extern "C" void kernel_launch(void* const* d_in, const int* in_sizes, int n_in,
                              void* d_out, int out_size, void* d_ws, size_t ws_size,
                              hipStream_t stream) {
    const float* FF  = (const float*)d_in[0];
    const float* Psi = (const float*)d_in[1];
    const float* im  = (const float*)d_in[2];
    float* out = (float*)d_out;
    char* ws = (char*)d_ws;
    size_t off = 0;
    auto alloc = [&](size_t bytes) {
        size_t o = off;
        off += (bytes + 255) & ~(size_t)255;
        return o;
    };
    unsigned short* FFnb  = (unsigned short*)(ws + alloc((size_t)NN * CC * 2));
    unsigned char* res20  = (unsigned char*)(ws + alloc((size_t)8 * HWP * HWP));
    unsigned char* res10  = (unsigned char*)(ws + alloc((size_t)8 * HWP * HWP));
    float* rowsum         = (float*)(ws + alloc((size_t)NN * 4));
    float* Dv             = (float*)(ws + alloc((size_t)NN * 4));
    unsigned short* PaT   = (unsigned short*)(ws + alloc((size_t)KD * NN * 2));
    unsigned short* PsT   = (unsigned short*)(ws + alloc((size_t)KD * NN * 2));
    unsigned short* YT    = (unsigned short*)(ws + alloc((size_t)KD * NN * 2));
    float* YTacc          = (float*)(ws + alloc((size_t)KD * NN * 4));
    float* R              = (float*)(ws + alloc((size_t)KD * KD * 4));
    float* acc2           = (float*)(ws + alloc(256));
    unsigned short* A     = (unsigned short*)(ws + alloc((size_t)NN * NN * 2));

    hipMemsetAsync(rowsum, 0, (size_t)NN * 4, stream);
    hipMemsetAsync(YTacc, 0, (size_t)KD * NN * 4, stream);
    hipMemsetAsync(R, 0, (size_t)KD * KD * 4, stream);
    hipMemsetAsync(acc2, 0, 8, stream);

    k_normalize<<<NN, 128, 0, stream>>>(FF, FFnb);
    k_knn<<<4096, 256, 0, stream>>>(im, res20, res10);
    k_gram<<<2080, 256, 0, stream>>>(FFnb, res20, res10, A, rowsum);
    k_d<<<NN / 256, 256, 0, stream>>>(rowsum, Dv);
    k_psiT<<<dim3(128, 4), 256, 0, stream>>>(Psi, Dv, PaT, PsT);
    k_ytks<<<1024, 256, 0, stream>>>(PsT, A, YTacc);
    k_ytfin<<<(KD * NN) / (256 * 8), 256, 0, stream>>>(YTacc, Dv, YT);
    k_r<<<dim3(10, 8), 256, 0, stream>>>(PaT, YT, R);
    k_tri<<<64, 256, 0, stream>>>(R, acc2);
    k_fin<<<1, 1, 0, stream>>>(acc2, out);
}